// Round 2
// baseline (370.415 us; speedup 1.0000x reference)
//
#include <hip/hip_runtime.h>
#include <hip/hip_bf16.h>
#include <math.h>

#define DDIM 768
#define NCLS 256
#define NFEAT 768
#define NTOK 1024
#define NBATCH 4
#define KSEL 128

// ---------------- helpers ----------------
__device__ __forceinline__ float wsum(float v) {
#pragma unroll
  for (int o = 32; o; o >>= 1) v += __shfl_down(v, o, 64);
  return v;
}
__device__ __forceinline__ float wmaxr(float v) {
#pragma unroll
  for (int o = 32; o; o >>= 1) v = fmaxf(v, __shfl_down(v, o, 64));
  return v;
}
__device__ __forceinline__ float ftanh(float x) {
  float t = __expf(-2.f * fabsf(x));
  float r = (1.f - t) / (1.f + t);
  return copysignf(r, x);
}

// ---------------- GEMM: C[M,N] = act(A[M,K] @ W[K,N] + bias) (+addsrc) ----
// mode 0: A is plain [M,K]
// mode 1: rows are concat(cls[b,256,K], feats[b,768,K]) per batch of 1024 rows
// act 0: none; 1: leaky(0.01); 2: leaky + addsrc
__global__ __launch_bounds__(256) void gemm_bias_act(
    const float* __restrict__ A, const float* __restrict__ A2,
    const float* __restrict__ W, const float* __restrict__ bias,
    const float* __restrict__ addsrc, float* __restrict__ C,
    int M, int N, int K, int mode, int act) {
  __shared__ __align__(16) float As[16][64];
  __shared__ __align__(16) float Ws[16][64];
  const int tid = threadIdx.x;
  const int row0 = blockIdx.y * 64;
  const int col0 = blockIdx.x * 64;
  const int ty = tid >> 4, tx = tid & 15;
  const int ai = tid >> 2;         // tile row for A load
  const int ak = (tid & 3) << 2;   // k offset (x4)
  const int wk = tid >> 4;         // tile k for W load
  const int wj = (tid & 15) << 2;  // col offset (x4)

  const float* arow;
  {
    int gr = row0 + ai;
    if (mode == 0) {
      arow = A + (size_t)gr * K;
    } else {
      int b = gr >> 10, rr = gr & 1023;
      arow = (rr < NCLS) ? (A + ((size_t)b * NCLS + rr) * K)
                         : (A2 + ((size_t)b * NFEAT + (rr - NCLS)) * K);
    }
  }

  float acc[4][4] = {};
  for (int k0 = 0; k0 < K; k0 += 16) {
    float4 av = *(const float4*)(arow + k0 + ak);
    float4 wv = *(const float4*)(W + (size_t)(k0 + wk) * N + col0 + wj);
    As[ak + 0][ai] = av.x;
    As[ak + 1][ai] = av.y;
    As[ak + 2][ai] = av.z;
    As[ak + 3][ai] = av.w;
    *(float4*)&Ws[wk][wj] = wv;
    __syncthreads();
#pragma unroll
    for (int kk = 0; kk < 16; ++kk) {
      float4 a = *(const float4*)&As[kk][ty << 2];
      float4 b = *(const float4*)&Ws[kk][tx << 2];
      float avv[4] = {a.x, a.y, a.z, a.w};
      float bvv[4] = {b.x, b.y, b.z, b.w};
#pragma unroll
      for (int mi = 0; mi < 4; ++mi)
#pragma unroll
        for (int ni = 0; ni < 4; ++ni)
          acc[mi][ni] = fmaf(avv[mi], bvv[ni], acc[mi][ni]);
    }
    __syncthreads();
  }

  const int r0 = row0 + (ty << 2);
  const int c0 = col0 + (tx << 2);
#pragma unroll
  for (int mi = 0; mi < 4; ++mi) {
#pragma unroll
    for (int ni = 0; ni < 4; ++ni) {
      int cc = c0 + ni;
      float v = acc[mi][ni] + bias[cc];
      if (act >= 1) v = v > 0.f ? v : 0.01f * v;
      if (act == 2) v += addsrc[(size_t)(r0 + mi) * N + cc];
      C[(size_t)(r0 + mi) * N + cc] = v;
    }
  }
}

// -------- logits: C[b,256,1024] = scale * e_h[b] @ e_t[b]^T --------
__global__ __launch_bounds__(256) void gemm_nt_scale(
    const float* __restrict__ Eh, const float* __restrict__ Et,
    float* __restrict__ C, float scale) {
  const int b = blockIdx.z;
  const float* A = Eh + (size_t)b * NCLS * DDIM;
  const float* Bt = Et + (size_t)b * NTOK * DDIM;
  float* Cb = C + (size_t)b * NCLS * NTOK;
  __shared__ __align__(16) float As[16][64];
  __shared__ __align__(16) float Bs[16][64];
  const int tid = threadIdx.x;
  const int row0 = blockIdx.y * 64;
  const int col0 = blockIdx.x * 64;
  const int ty = tid >> 4, tx = tid & 15;
  const int ai = tid >> 2;
  const int ak = (tid & 3) << 2;

  float acc[4][4] = {};
  for (int k0 = 0; k0 < DDIM; k0 += 16) {
    float4 av = *(const float4*)(A + (size_t)(row0 + ai) * DDIM + k0 + ak);
    float4 bv = *(const float4*)(Bt + (size_t)(col0 + ai) * DDIM + k0 + ak);
    As[ak + 0][ai] = av.x;
    As[ak + 1][ai] = av.y;
    As[ak + 2][ai] = av.z;
    As[ak + 3][ai] = av.w;
    Bs[ak + 0][ai] = bv.x;
    Bs[ak + 1][ai] = bv.y;
    Bs[ak + 2][ai] = bv.z;
    Bs[ak + 3][ai] = bv.w;
    __syncthreads();
#pragma unroll
    for (int kk = 0; kk < 16; ++kk) {
      float4 a = *(const float4*)&As[kk][ty << 2];
      float4 b = *(const float4*)&Bs[kk][tx << 2];
      float avv[4] = {a.x, a.y, a.z, a.w};
      float bvv[4] = {b.x, b.y, b.z, b.w};
#pragma unroll
      for (int mi = 0; mi < 4; ++mi)
#pragma unroll
        for (int ni = 0; ni < 4; ++ni)
          acc[mi][ni] = fmaf(avv[mi], bvv[ni], acc[mi][ni]);
    }
    __syncthreads();
  }
  const int r0 = row0 + (ty << 2);
  const int c0 = col0 + (tx << 2);
#pragma unroll
  for (int mi = 0; mi < 4; ++mi)
#pragma unroll
    for (int ni = 0; ni < 4; ++ni)
      Cb[(size_t)(r0 + mi) * NTOK + c0 + ni] = scale * acc[mi][ni];
}

// -------- top-k: full bitonic sort of 1024 (desc, tie -> smaller idx) -----
__global__ __launch_bounds__(512) void topk_kernel(
    const float* __restrict__ logits, float* __restrict__ tw,
    int* __restrict__ ti) {
  const int row = blockIdx.x;  // b*256+n
  __shared__ float v[NTOK];
  __shared__ int id[NTOK];
  const int t = threadIdx.x;
  for (int i = t; i < NTOK; i += 512) {
    v[i] = logits[(size_t)row * NTOK + i];
    id[i] = i;
  }
  __syncthreads();
  for (int k = 2; k <= NTOK; k <<= 1) {
    for (int j = k >> 1; j > 0; j >>= 1) {
      int i = ((t & ~(j - 1)) << 1) | (t & (j - 1));
      int p = i | j;
      float va = v[i], vb = v[p];
      int ia = id[i], ib = id[p];
      bool aFirst = (va > vb) || (va == vb && ia < ib);
      bool desc = ((i & k) == 0);
      if (desc ? !aFirst : aFirst) {
        v[i] = vb;
        v[p] = va;
        id[i] = ib;
        id[p] = ia;
      }
      __syncthreads();
    }
  }
  if (t < KSEL) {
    tw[(size_t)row * KSEL + t] = v[t];
    ti[(size_t)row * KSEL + t] = id[t];
  }
}

// -------- aggregation: topk softmax, gated ka weights, e_Nh, lin inputs ----
__global__ __launch_bounds__(256) void agg_kernel(
    const float* __restrict__ e_h, const float* __restrict__ e_t,
    const float* __restrict__ cls, const float* __restrict__ tw,
    const int* __restrict__ ti, float* __restrict__ sum_in,
    float* __restrict__ bi_in) {
  const int row = blockIdx.x;  // b*256+n
  const int b = row >> 8;
  const int t = threadIdx.x;
  const int lane = t & 63, wave = t >> 6;
  __shared__ float ehs[DDIM];
  __shared__ float p[KSEL];
  __shared__ float kaw[KSEL];
  __shared__ int idx_s[KSEL];
  __shared__ float red[4];

  float eh[3];
#pragma unroll
  for (int c = 0; c < 3; ++c) {
    eh[c] = e_h[(size_t)row * DDIM + t + 256 * c];
    ehs[t + 256 * c] = eh[c];
  }
  if (t < KSEL) {
    p[t] = tw[(size_t)row * KSEL + t];
    idx_s[t] = ti[(size_t)row * KSEL + t];
  }
  __syncthreads();

  // softmax over topk weights -> p[]
  if (wave == 0) {
    float m = fmaxf(p[lane], p[lane + 64]);
    m = wmaxr(m);
    if (lane == 0) red[0] = m;
  }
  __syncthreads();
  float m0 = red[0];
  if (t < KSEL) p[t] = __expf(p[t] - m0);
  __syncthreads();
  if (wave == 0) {
    float s = p[lane] + p[lane + 64];
    s = wsum(s);
    if (lane == 0) red[1] = s;
  }
  __syncthreads();
  if (t < KSEL) p[t] *= (1.f / red[1]);
  __syncthreads();

  // pass 1: ka_weight[j] = dot(Nb_j, tanh((2-p_j)*e_h + p_j*Nb_j))
  for (int j = wave; j < KSEL; j += 4) {
    const float pj = p[j];
    const float* nb = e_t + ((size_t)(b << 10) + idx_s[j]) * DDIM;
    float partial = 0.f;
#pragma unroll
    for (int c = 0; c < 12; ++c) {
      float nv = nb[lane + (c << 6)];
      float ev = ehs[lane + (c << 6)];
      float g = ftanh((2.f - pj) * ev + pj * nv);
      partial = fmaf(nv, g, partial);
    }
    partial = wsum(partial);
    if (lane == 0) kaw[j] = partial;
  }
  __syncthreads();

  // softmax over kaw -> probabilities
  if (wave == 0) {
    float m = fmaxf(kaw[lane], kaw[lane + 64]);
    m = wmaxr(m);
    if (lane == 0) red[2] = m;
  }
  __syncthreads();
  float km = red[2];
  if (t < KSEL) kaw[t] = __expf(kaw[t] - km);
  __syncthreads();
  if (wave == 0) {
    float s = kaw[lane] + kaw[lane + 64];
    s = wsum(s);
    if (lane == 0) red[3] = s;
  }
  __syncthreads();
  if (t < KSEL) kaw[t] *= (1.f / red[3]);
  __syncthreads();

  // pass 2: e_Nh = sum_j kaw[j] * Nb_j   (each thread owns 3 d-slots)
  float acc[3] = {0.f, 0.f, 0.f};
  for (int j = 0; j < KSEL; ++j) {
    float pr = kaw[j];
    const float* nb = e_t + ((size_t)(b << 10) + idx_s[j]) * DDIM;
#pragma unroll
    for (int c = 0; c < 3; ++c) acc[c] = fmaf(pr, nb[t + 256 * c], acc[c]);
  }

#pragma unroll
  for (int c = 0; c < 3; ++c) {
    size_t o = (size_t)row * DDIM + t + 256 * c;
    float cv = cls[o];
    sum_in[o] = (eh[c] + acc[c]) * 0.1f + cv;
    bi_in[o] = (eh[c] * acc[c]) * 0.1f + cv;
  }
}

// -------- layernorm over D=768 --------
__global__ __launch_bounds__(256) void ln_kernel(const float* __restrict__ emb,
                                                 const float* __restrict__ lw,
                                                 const float* __restrict__ lb,
                                                 float* __restrict__ out) {
  const int row = blockIdx.x;
  const int t = threadIdx.x;
  const int lane = t & 63, wave = t >> 6;
  __shared__ float red[4];
  __shared__ float bs[2];
  float e[3];
#pragma unroll
  for (int c = 0; c < 3; ++c) e[c] = emb[(size_t)row * DDIM + t + 256 * c];
  float s = e[0] + e[1] + e[2];
  s = wsum(s);
  if (lane == 0) red[wave] = s;
  __syncthreads();
  if (t == 0) bs[0] = (red[0] + red[1] + red[2] + red[3]) * (1.f / DDIM);
  __syncthreads();
  float mu = bs[0];
  float q = 0.f;
#pragma unroll
  for (int c = 0; c < 3; ++c) {
    float d = e[c] - mu;
    q = fmaf(d, d, q);
  }
  q = wsum(q);
  if (lane == 0) red[wave] = q;
  __syncthreads();
  if (t == 0) bs[1] = (red[0] + red[1] + red[2] + red[3]) * (1.f / DDIM);
  __syncthreads();
  float rstd = rsqrtf(bs[1] + 1e-5f);
#pragma unroll
  for (int c = 0; c < 3; ++c) {
    int d = t + 256 * c;
    out[(size_t)row * DDIM + d] = (e[c] - mu) * rstd * lw[d] + lb[d];
  }
}

// ---------------- launch ----------------
extern "C" void kernel_launch(void* const* d_in, const int* in_sizes, int n_in,
                              void* d_out, int out_size, void* d_ws,
                              size_t ws_size, hipStream_t stream) {
  const float* cls = (const float*)d_in[0];
  const float* feats = (const float*)d_in[1];
  const float* Whw = (const float*)d_in[2];
  const float* Whb = (const float*)d_in[3];
  const float* Wtw = (const float*)d_in[4];
  const float* Wtb = (const float*)d_in[5];
  const float* l1w = (const float*)d_in[6];
  const float* l1b = (const float*)d_in[7];
  const float* l2w = (const float*)d_in[8];
  const float* l2b = (const float*)d_in[9];
  const float* lnw = (const float*)d_in[10];
  const float* lnb = (const float*)d_in[11];
  float* out = (float*)d_out;

  float* ws = (float*)d_ws;
  float* e_h = ws + 0;                    //  786432
  float* e_t = ws + 786432;               // 3145728
  float* logits = ws + 3932160;           // 1048576
  float* tw = ws + 4980736;               //  131072
  int* ti = (int*)(ws + 5111808);         //  131072
  float* sum_in = ws + 5242880;           //  786432
  float* bi_in = ws + 6029312;            //  786432
  float* sum_emb = ws + 6815744;          //  786432
  float* emb = ws + 7602176;              //  786432
  (void)ws_size;
  (void)in_sizes;
  (void)n_in;
  (void)out_size;

  const float scale = 0.036084391824351615f;  // 1/sqrt(768)
  dim3 blk(256);

  // e_h = cls @ W_head + b
  gemm_bias_act<<<dim3(DDIM / 64, (NBATCH * NCLS) / 64), blk, 0, stream>>>(
      cls, nullptr, Whw, Whb, nullptr, e_h, NBATCH * NCLS, DDIM, DDIM, 0, 0);
  // e_t = concat(cls,feats) @ W_tail + b
  gemm_bias_act<<<dim3(DDIM / 64, (NBATCH * NTOK) / 64), blk, 0, stream>>>(
      cls, feats, Wtw, Wtb, nullptr, e_t, NBATCH * NTOK, DDIM, DDIM, 1, 0);
  // logits = scale * e_h @ e_t^T (per batch)
  gemm_nt_scale<<<dim3(NTOK / 64, NCLS / 64, NBATCH), blk, 0, stream>>>(
      e_h, e_t, logits, scale);
  // top-128 per row
  topk_kernel<<<dim3(NBATCH * NCLS), dim3(512), 0, stream>>>(logits, tw, ti);
  // aggregation -> lin inputs
  agg_kernel<<<dim3(NBATCH * NCLS), blk, 0, stream>>>(e_h, e_t, cls, tw, ti,
                                                      sum_in, bi_in);
  // sum_emb = leaky(sum_in @ lin1 + b1)
  gemm_bias_act<<<dim3(DDIM / 64, (NBATCH * NCLS) / 64), blk, 0, stream>>>(
      sum_in, nullptr, l1w, l1b, nullptr, sum_emb, NBATCH * NCLS, DDIM, DDIM, 0,
      1);
  // emb = leaky(bi_in @ lin2 + b2) + sum_emb
  gemm_bias_act<<<dim3(DDIM / 64, (NBATCH * NCLS) / 64), blk, 0, stream>>>(
      bi_in, nullptr, l2w, l2b, sum_emb, emb, NBATCH * NCLS, DDIM, DDIM, 0, 2);
  // layernorm -> out
  ln_kernel<<<dim3(NBATCH * NCLS), blk, 0, stream>>>(emb, lnw, lnb, out);
}

// Round 3
// 278.442 us; speedup vs baseline: 1.3303x; 1.3303x over previous
//
#include <hip/hip_runtime.h>
#include <hip/hip_bf16.h>
#include <math.h>

#define DDIM 768
#define NCLS 256
#define NFEAT 768
#define NTOK 1024
#define NBATCH 4
#define KSEL 128

typedef float f32x4 __attribute__((ext_vector_type(4)));
typedef short s16x8 __attribute__((ext_vector_type(8)));

// ---------------- helpers ----------------
__device__ __forceinline__ float wsum(float v) {
#pragma unroll
  for (int o = 32; o; o >>= 1) v += __shfl_down(v, o, 64);
  return v;
}
__device__ __forceinline__ float wmaxr(float v) {
#pragma unroll
  for (int o = 32; o; o >>= 1) v = fmaxf(v, __shfl_down(v, o, 64));
  return v;
}
__device__ __forceinline__ float ftanh(float x) {
  float t = __expf(-2.f * fabsf(x));
  float r = (1.f - t) * __builtin_amdgcn_rcpf(1.f + t);
  return copysignf(r, x);
}
__device__ __forceinline__ short f2bf(float f) {
  __hip_bfloat16 h = __float2bfloat16(f);
  union { __hip_bfloat16 h; short s; } u;
  u.h = h;
  return u.s;
}
__device__ __forceinline__ float bf2f(short s) {
  union { unsigned u; float f; } c;
  c.u = ((unsigned)(unsigned short)s) << 16;
  return c.f;
}
__device__ __forceinline__ void cvt8(float4 x, float4 y, s16x8& h, s16x8& l,
                                     bool split) {
  float v[8] = {x.x, x.y, x.z, x.w, y.x, y.y, y.z, y.w};
#pragma unroll
  for (int i = 0; i < 8; ++i) {
    short hh = f2bf(v[i]);
    h[i] = hh;
    if (split) l[i] = f2bf(v[i] - bf2f(hh));
  }
}

// -------- transpose two 768x768 fp32 matrices (z selects pair) --------
__global__ __launch_bounds__(256) void transpose2(
    const float* __restrict__ s0, float* __restrict__ d0,
    const float* __restrict__ s1, float* __restrict__ d1) {
  __shared__ float tile[32][33];
  const float* s = blockIdx.z ? s1 : s0;
  float* d = blockIdx.z ? d1 : d0;
  const int tx = threadIdx.x & 31, ty0 = threadIdx.x >> 5;
  const int r0 = blockIdx.y * 32, c0 = blockIdx.x * 32;
#pragma unroll
  for (int i = 0; i < 4; ++i) {
    int ty = ty0 + i * 8;
    tile[ty][tx] = s[(size_t)(r0 + ty) * DDIM + c0 + tx];
  }
  __syncthreads();
#pragma unroll
  for (int i = 0; i < 4; ++i) {
    int ty = ty0 + i * 8;
    d[(size_t)(c0 + ty) * DDIM + r0 + tx] = tile[tx][ty];
  }
}

// -------- NT MFMA GEMM: C[M,N] = act(A[M,K] @ B[N,K]^T * scale + bias) ----
// SPLIT=1: hi/lo split-bf16 (3 MFMAs) for ~fp32 accuracy.
// mode 1: A rows are concat(cls[b,256,K], feats[b,768,K]) per 1024-row batch.
// Mcut: row tiles >= Mcut use B2/bias2 (fused lin1/lin2).
template <int SPLIT>
__global__ __launch_bounds__(256) void gemm_nt(
    const float* __restrict__ A, const float* __restrict__ A2,
    const float* __restrict__ B, const float* __restrict__ B2,
    const float* __restrict__ bias, const float* __restrict__ bias2,
    float* __restrict__ C, int N, int K, int mode, int act, int Mcut,
    float outscale, long aStride, long bStride, long cStride) {
  __shared__ short Ah[128 * 40];
  __shared__ short Bh[128 * 40];
  __shared__ short Al[SPLIT ? 128 * 40 : 8];
  __shared__ short Bl[SPLIT ? 128 * 40 : 8];

  const int t = threadIdx.x;
  const int z = blockIdx.z;
  const int row0 = blockIdx.y * 128;
  const int col0 = blockIdx.x * 128;
  const bool second = (row0 >= Mcut);
  const float* Bu = second ? B2 : B;
  const float* biasu = second ? bias2 : bias;
  const float* Bb = Bu + (size_t)z * bStride;

  const int sr = t >> 1;            // staged row 0..127
  const int sk = (t & 1) * 16;      // k offset 0/16

  const float* aptr;
  {
    int gr = row0 + sr;
    if (mode == 1) {
      int b = gr >> 10, rr = gr & 1023;
      aptr = (rr < NCLS) ? (A + ((size_t)b * NCLS + rr) * K)
                         : (A2 + ((size_t)b * NFEAT + (rr - NCLS)) * K);
    } else {
      aptr = A + (size_t)z * aStride + (size_t)gr * K;
    }
    aptr += sk;
  }
  const float* bptr = Bb + (size_t)(col0 + sr) * K + sk;

  const int lane = t & 63, wave = t >> 6;
  const int wr = wave >> 1, wc = wave & 1;
  const int fr = lane & 15;   // frag row (A) / col (B,C)
  const int fq = lane >> 4;   // quarter

  f32x4 acc[4][4] = {};

  for (int k0 = 0; k0 < K; k0 += 32) {
    float4 a0 = *(const float4*)(aptr + k0);
    float4 a1 = *(const float4*)(aptr + k0 + 4);
    float4 a2 = *(const float4*)(aptr + k0 + 8);
    float4 a3 = *(const float4*)(aptr + k0 + 12);
    float4 b0 = *(const float4*)(bptr + k0);
    float4 b1 = *(const float4*)(bptr + k0 + 4);
    float4 b2 = *(const float4*)(bptr + k0 + 8);
    float4 b3 = *(const float4*)(bptr + k0 + 12);

    s16x8 ah0, ah1, al0, al1, bh0, bh1, bl0, bl1;
    cvt8(a0, a1, ah0, al0, SPLIT);
    cvt8(a2, a3, ah1, al1, SPLIT);
    cvt8(b0, b1, bh0, bl0, SPLIT);
    cvt8(b2, b3, bh1, bl1, SPLIT);

    __syncthreads();  // previous iter's reads complete
    *(s16x8*)&Ah[sr * 40 + sk] = ah0;
    *(s16x8*)&Ah[sr * 40 + sk + 8] = ah1;
    *(s16x8*)&Bh[sr * 40 + sk] = bh0;
    *(s16x8*)&Bh[sr * 40 + sk + 8] = bh1;
    if (SPLIT) {
      *(s16x8*)&Al[sr * 40 + sk] = al0;
      *(s16x8*)&Al[sr * 40 + sk + 8] = al1;
      *(s16x8*)&Bl[sr * 40 + sk] = bl0;
      *(s16x8*)&Bl[sr * 40 + sk + 8] = bl1;
    }
    __syncthreads();

    s16x8 afh[4], afl[4];
#pragma unroll
    for (int m = 0; m < 4; ++m) {
      int ro = (wr * 64 + m * 16 + fr) * 40 + fq * 8;
      afh[m] = *(const s16x8*)&Ah[ro];
      if (SPLIT) afl[m] = *(const s16x8*)&Al[ro];
    }
#pragma unroll
    for (int n = 0; n < 4; ++n) {
      int ro = (wc * 64 + n * 16 + fr) * 40 + fq * 8;
      s16x8 bfh = *(const s16x8*)&Bh[ro];
      s16x8 bfl;
      if (SPLIT) bfl = *(const s16x8*)&Bl[ro];
#pragma unroll
      for (int m = 0; m < 4; ++m) {
        acc[m][n] =
            __builtin_amdgcn_mfma_f32_16x16x32_bf16(afh[m], bfh, acc[m][n], 0, 0, 0);
        if (SPLIT) {
          acc[m][n] = __builtin_amdgcn_mfma_f32_16x16x32_bf16(afh[m], bfl,
                                                              acc[m][n], 0, 0, 0);
          acc[m][n] = __builtin_amdgcn_mfma_f32_16x16x32_bf16(afl[m], bfh,
                                                              acc[m][n], 0, 0, 0);
        }
      }
    }
  }

  float* Cb = C + (size_t)z * cStride;
#pragma unroll
  for (int m = 0; m < 4; ++m) {
#pragma unroll
    for (int n = 0; n < 4; ++n) {
#pragma unroll
      for (int r = 0; r < 4; ++r) {
        int rg = row0 + wr * 64 + m * 16 + fq * 4 + r;
        int cg = col0 + wc * 64 + n * 16 + fr;
        float v = acc[m][n][r] * outscale;
        if (biasu) v += biasu[cg];
        if (act) v = v > 0.f ? v : 0.01f * v;
        Cb[(size_t)rg * N + cg] = v;
      }
    }
  }
}

// -------- top-k: full bitonic sort of 1024 (desc, tie -> smaller idx) -----
__global__ __launch_bounds__(512) void topk_kernel(
    const float* __restrict__ logits, float* __restrict__ tw,
    int* __restrict__ ti) {
  const int row = blockIdx.x;
  __shared__ float v[NTOK];
  __shared__ int id[NTOK];
  const int t = threadIdx.x;
  for (int i = t; i < NTOK; i += 512) {
    v[i] = logits[(size_t)row * NTOK + i];
    id[i] = i;
  }
  __syncthreads();
  for (int k = 2; k <= NTOK; k <<= 1) {
    for (int j = k >> 1; j > 0; j >>= 1) {
      int i = ((t & ~(j - 1)) << 1) | (t & (j - 1));
      int p = i | j;
      float va = v[i], vb = v[p];
      int ia = id[i], ib = id[p];
      bool aFirst = (va > vb) || (va == vb && ia < ib);
      bool desc = ((i & k) == 0);
      if (desc ? !aFirst : aFirst) {
        v[i] = vb;
        v[p] = va;
        id[i] = ib;
        id[p] = ia;
      }
      __syncthreads();
    }
  }
  if (t < KSEL) {
    tw[(size_t)row * KSEL + t] = v[t];
    ti[(size_t)row * KSEL + t] = id[t];
  }
}

// -------- aggregation (XCD-swizzled: each XCD serves one batch) ----------
__global__ __launch_bounds__(256) void agg_kernel(
    const float* __restrict__ e_h, const float* __restrict__ e_t,
    const float* __restrict__ cls, const float* __restrict__ tw,
    const int* __restrict__ ti, float* __restrict__ sum_in,
    float* __restrict__ bi_in) {
  const int bid = blockIdx.x;
  const int xcd = bid & 7, slot = bid >> 3;
  const int row = (xcd >> 1) * 256 + (xcd & 1) * 128 + slot;  // b = xcd>>1
  const int b = row >> 8;
  const int t = threadIdx.x;
  const int lane = t & 63, wave = t >> 6;
  __shared__ float ehs[DDIM];
  __shared__ float p[KSEL];
  __shared__ float kaw[KSEL];
  __shared__ int idx_s[KSEL];
  __shared__ float red[4];

  float eh[3];
#pragma unroll
  for (int c = 0; c < 3; ++c) {
    eh[c] = e_h[(size_t)row * DDIM + t + 256 * c];
    ehs[t + 256 * c] = eh[c];
  }
  if (t < KSEL) {
    p[t] = tw[(size_t)row * KSEL + t];
    idx_s[t] = ti[(size_t)row * KSEL + t];
  }
  __syncthreads();

  if (wave == 0) {
    float m = fmaxf(p[lane], p[lane + 64]);
    m = wmaxr(m);
    if (lane == 0) red[0] = m;
  }
  __syncthreads();
  float m0 = red[0];
  if (t < KSEL) p[t] = __expf(p[t] - m0);
  __syncthreads();
  if (wave == 0) {
    float s = p[lane] + p[lane + 64];
    s = wsum(s);
    if (lane == 0) red[1] = s;
  }
  __syncthreads();
  if (t < KSEL) p[t] *= (1.f / red[1]);
  __syncthreads();

  for (int j = wave; j < KSEL; j += 4) {
    const float pj = p[j];
    const float* nb = e_t + ((size_t)(b << 10) + idx_s[j]) * DDIM;
    float partial = 0.f;
#pragma unroll
    for (int c = 0; c < 12; ++c) {
      float nv = nb[lane + (c << 6)];
      float ev = ehs[lane + (c << 6)];
      float g = ftanh((2.f - pj) * ev + pj * nv);
      partial = fmaf(nv, g, partial);
    }
    partial = wsum(partial);
    if (lane == 0) kaw[j] = partial;
  }
  __syncthreads();

  if (wave == 0) {
    float m = fmaxf(kaw[lane], kaw[lane + 64]);
    m = wmaxr(m);
    if (lane == 0) red[2] = m;
  }
  __syncthreads();
  float km = red[2];
  if (t < KSEL) kaw[t] = __expf(kaw[t] - km);
  __syncthreads();
  if (wave == 0) {
    float s = kaw[lane] + kaw[lane + 64];
    s = wsum(s);
    if (lane == 0) red[3] = s;
  }
  __syncthreads();
  if (t < KSEL) kaw[t] *= (1.f / red[3]);
  __syncthreads();

  float acc[3] = {0.f, 0.f, 0.f};
  for (int j = 0; j < KSEL; ++j) {
    float pr = kaw[j];
    const float* nb = e_t + ((size_t)(b << 10) + idx_s[j]) * DDIM;
#pragma unroll
    for (int c = 0; c < 3; ++c) acc[c] = fmaf(pr, nb[t + 256 * c], acc[c]);
  }

#pragma unroll
  for (int c = 0; c < 3; ++c) {
    size_t o = (size_t)row * DDIM + t + 256 * c;
    float cv = cls[o];
    sum_in[o] = (eh[c] + acc[c]) * 0.1f + cv;
    bi_in[o] = (eh[c] * acc[c]) * 0.1f + cv;
  }
}

// -------- layernorm over D=768 on (embA[row] + embB[row]) --------
__global__ __launch_bounds__(256) void ln_kernel(const float* __restrict__ embA,
                                                 const float* __restrict__ embB,
                                                 const float* __restrict__ lw,
                                                 const float* __restrict__ lb,
                                                 float* __restrict__ out) {
  const int row = blockIdx.x;
  const int t = threadIdx.x;
  const int lane = t & 63, wave = t >> 6;
  __shared__ float red[4];
  __shared__ float bs[2];
  float e[3];
#pragma unroll
  for (int c = 0; c < 3; ++c) {
    size_t o = (size_t)row * DDIM + t + 256 * c;
    e[c] = embA[o] + embB[o];
  }
  float s = e[0] + e[1] + e[2];
  s = wsum(s);
  if (lane == 0) red[wave] = s;
  __syncthreads();
  if (t == 0) bs[0] = (red[0] + red[1] + red[2] + red[3]) * (1.f / DDIM);
  __syncthreads();
  float mu = bs[0];
  float q = 0.f;
#pragma unroll
  for (int c = 0; c < 3; ++c) {
    float d = e[c] - mu;
    q = fmaf(d, d, q);
  }
  q = wsum(q);
  if (lane == 0) red[wave] = q;
  __syncthreads();
  if (t == 0) bs[1] = (red[0] + red[1] + red[2] + red[3]) * (1.f / DDIM);
  __syncthreads();
  float rstd = rsqrtf(bs[1] + 1e-5f);
#pragma unroll
  for (int c = 0; c < 3; ++c) {
    int d = t + 256 * c;
    out[(size_t)row * DDIM + d] = (e[c] - mu) * rstd * lw[d] + lb[d];
  }
}

// ---------------- launch ----------------
extern "C" void kernel_launch(void* const* d_in, const int* in_sizes, int n_in,
                              void* d_out, int out_size, void* d_ws,
                              size_t ws_size, hipStream_t stream) {
  const float* cls = (const float*)d_in[0];
  const float* feats = (const float*)d_in[1];
  const float* Whw = (const float*)d_in[2];
  const float* Whb = (const float*)d_in[3];
  const float* Wtw = (const float*)d_in[4];
  const float* Wtb = (const float*)d_in[5];
  const float* l1w = (const float*)d_in[6];
  const float* l1b = (const float*)d_in[7];
  const float* l2w = (const float*)d_in[8];
  const float* l2b = (const float*)d_in[9];
  const float* lnw = (const float*)d_in[10];
  const float* lnb = (const float*)d_in[11];
  float* out = (float*)d_out;

  float* ws = (float*)d_ws;
  float* e_h = ws;                   // 786432
  float* e_t = ws + 786432;          // 3145728; later sum_emb/bi_emb overlay
  float* scr = ws + 3932160;         // 1179648: WhT/WtT -> logits -> L1T/L2T
  float* tw = ws + 5111808;          // 131072
  int* ti = (int*)(ws + 5242880);    // 131072
  float* sum_in = ws + 5373952;      // 786432
  float* bi_in = ws + 6160384;       // 786432 (contiguous after sum_in)
  float* WhT = scr;
  float* WtT = scr + 589824;
  float* logits = scr;
  float* L1T = scr;
  float* L2T = scr + 589824;
  float* sum_emb = e_t;              // e_t dead after agg
  float* bi_emb = e_t + 786432;
  (void)ws_size;
  (void)in_sizes;
  (void)n_in;
  (void)out_size;

  const float scale = 0.036084391824351615f;  // 1/sqrt(768)
  const int BIG = 1 << 30;
  dim3 blk(256);

  // W_head^T, W_tail^T
  transpose2<<<dim3(24, 24, 2), blk, 0, stream>>>(Whw, WhT, Wtw, WtT);
  // e_h = cls @ Wh + b (split precision)
  gemm_nt<1><<<dim3(6, 8, 1), blk, 0, stream>>>(
      cls, nullptr, WhT, nullptr, Whb, nullptr, e_h, DDIM, DDIM, 0, 0, BIG,
      1.f, 0, 0, 0);
  // e_t = concat(cls,feats) @ Wt + b (split precision)
  gemm_nt<1><<<dim3(6, 32, 1), blk, 0, stream>>>(
      cls, feats, WtT, nullptr, Wtb, nullptr, e_t, DDIM, DDIM, 1, 0, BIG, 1.f,
      0, 0, 0);
  // logits[b] = scale * e_h[b] @ e_t[b]^T (split precision, batched)
  gemm_nt<1><<<dim3(8, 2, 4), blk, 0, stream>>>(
      e_h, nullptr, e_t, nullptr, nullptr, nullptr, logits, NTOK, DDIM, 0, 0,
      BIG, scale, (long)NCLS * DDIM, (long)NTOK * DDIM, (long)NCLS * NTOK);
  // top-128 per row
  topk_kernel<<<dim3(NBATCH * NCLS), dim3(512), 0, stream>>>(logits, tw, ti);
  // lin1^T, lin2^T (overwrites logits region — dead after topk)
  transpose2<<<dim3(24, 24, 2), blk, 0, stream>>>(l1w, L1T, l2w, L2T);
  // aggregation -> lin inputs
  agg_kernel<<<dim3(NBATCH * NCLS), blk, 0, stream>>>(e_h, e_t, cls, tw, ti,
                                                      sum_in, bi_in);
  // fused lin1/lin2: rows 0..1023 -> leaky(sum_in@l1+b1), 1024.. -> leaky(bi_in@l2+b2)
  gemm_nt<0><<<dim3(6, 16, 1), blk, 0, stream>>>(
      sum_in, nullptr, L1T, L2T, l1b, l2b, sum_emb, DDIM, DDIM, 0, 1, 1024,
      1.f, 0, 0, 0);
  // layernorm(sum_emb + bi_emb) -> out
  ln_kernel<<<dim3(NBATCH * NCLS), blk, 0, stream>>>(sum_emb, bi_emb, lnw, lnb,
                                                     out);
}

// Round 4
// 255.084 us; speedup vs baseline: 1.4521x; 1.0916x over previous
//
#include <hip/hip_runtime.h>
#include <hip/hip_bf16.h>
#include <math.h>

#define DDIM 768
#define NCLS 256
#define NFEAT 768
#define NTOK 1024
#define NBATCH 4
#define KSEL 128

typedef float f32x4 __attribute__((ext_vector_type(4)));
typedef short s16x8 __attribute__((ext_vector_type(8)));

// ---------------- helpers ----------------
__device__ __forceinline__ float wsum(float v) {
#pragma unroll
  for (int o = 32; o; o >>= 1) v += __shfl_down(v, o, 64);
  return v;
}
__device__ __forceinline__ float wmaxr(float v) {
#pragma unroll
  for (int o = 32; o; o >>= 1) v = fmaxf(v, __shfl_down(v, o, 64));
  return v;
}
__device__ __forceinline__ short f2bf(float f) {
  union { __hip_bfloat16 h; short s; } u;
  u.h = __float2bfloat16(f);
  return u.s;
}
__device__ __forceinline__ float bf2f(short s) {
  union { unsigned u; float f; } c;
  c.u = ((unsigned)(unsigned short)s) << 16;
  return c.f;
}
__device__ __forceinline__ void cvt8(float4 x, float4 y, s16x8& h, s16x8& l,
                                     bool split) {
  float v[8] = {x.x, x.y, x.z, x.w, y.x, y.y, y.z, y.w};
#pragma unroll
  for (int i = 0; i < 8; ++i) {
    short hh = f2bf(v[i]);
    h[i] = hh;
    if (split) l[i] = f2bf(v[i] - bf2f(hh));
  }
}

// -------- transpose + bf16-convert weights (z: 0=Wh split,1=Wt split,
//          2=L1 plain,3=L2 plain) --------
__global__ __launch_bounds__(256) void prep_weights(
    const float* __restrict__ w0, const float* __restrict__ w1,
    const float* __restrict__ w2, const float* __restrict__ w3,
    short* __restrict__ h0, short* __restrict__ h1, short* __restrict__ h2,
    short* __restrict__ h3, short* __restrict__ l0, short* __restrict__ l1) {
  __shared__ float tile[32][33];
  const int z = blockIdx.z;
  const float* s = z == 0 ? w0 : z == 1 ? w1 : z == 2 ? w2 : w3;
  short* dh = z == 0 ? h0 : z == 1 ? h1 : z == 2 ? h2 : h3;
  short* dl = z == 0 ? l0 : z == 1 ? l1 : nullptr;
  const int tx = threadIdx.x & 31, ty0 = threadIdx.x >> 5;
  const int r0 = blockIdx.y * 32, c0 = blockIdx.x * 32;
#pragma unroll
  for (int i = 0; i < 4; ++i) {
    int ty = ty0 + i * 8;
    tile[ty][tx] = s[(size_t)(r0 + ty) * DDIM + c0 + tx];
  }
  __syncthreads();
#pragma unroll
  for (int i = 0; i < 4; ++i) {
    int ty = ty0 + i * 8;
    float v = tile[tx][ty];
    short hh = f2bf(v);
    dh[(size_t)(c0 + ty) * DDIM + r0 + tx] = hh;
    if (dl) dl[(size_t)(c0 + ty) * DDIM + r0 + tx] = f2bf(v - bf2f(hh));
  }
}

// -------- NT MFMA GEMM: C[M,N] = act((A @ B^T)*scale + bias) --------
// SPLIT: 3-MFMA hi/lo split (≈fp32 acc). ABF: A given as bf16 hi/lo.
// WOUT: also emit C as bf16 hi/lo. mode1 (ABF=0): A rows = concat(cls,feats).
// Row tiles >= Mcut use B2hh/bias2 (fused lin1/lin2; SPLIT=0 only).
template <int SPLIT, int ABF, int WOUT>
__global__ __launch_bounds__(256) void gemm_nt(
    const float* __restrict__ Af, const float* __restrict__ A2f,
    const short* __restrict__ Ahh, const short* __restrict__ All,
    const short* __restrict__ Bhh, const short* __restrict__ Bll,
    const short* __restrict__ B2hh, const float* __restrict__ bias,
    const float* __restrict__ bias2, float* __restrict__ C,
    short* __restrict__ Chi, short* __restrict__ Clo, int N, int K, int mode,
    int act, int Mcut, float outscale, long aStride, long bStride,
    long cStride) {
  __shared__ short Ah[128 * 40];
  __shared__ short Bh[128 * 40];
  __shared__ short Al[SPLIT ? 128 * 40 : 8];
  __shared__ short Bl[SPLIT ? 128 * 40 : 8];

  const int t = threadIdx.x;
  const int z = blockIdx.z;
  const int row0 = blockIdx.y * 128;
  const int col0 = blockIdx.x * 128;
  const bool second = (row0 >= Mcut);
  const float* biasu = second ? bias2 : bias;

  const int sr = t >> 1;        // staged row 0..127
  const int sk = (t & 1) * 16;  // k offset 0/16

  // A-side source pointers
  const float* aptrF = nullptr;
  const short* aptrH = nullptr;
  const short* aptrL = nullptr;
  {
    int gr = row0 + sr;
    if (ABF) {
      aptrH = Ahh + (size_t)z * aStride + (size_t)gr * K + sk;
      if (SPLIT) aptrL = All + (size_t)z * aStride + (size_t)gr * K + sk;
    } else if (mode == 1) {
      int b = gr >> 10, rr = gr & 1023;
      aptrF = (rr < NCLS) ? (Af + ((size_t)b * NCLS + rr) * K)
                          : (A2f + ((size_t)b * NFEAT + (rr - NCLS)) * K);
      aptrF += sk;
    } else {
      aptrF = Af + (size_t)z * aStride + (size_t)gr * K + sk;
    }
  }
  const short* Bsel = second ? B2hh : Bhh;
  const short* bptrH = Bsel + (size_t)z * bStride + (size_t)(col0 + sr) * K + sk;
  const short* bptrL =
      SPLIT ? (Bll + (size_t)z * bStride + (size_t)(col0 + sr) * K + sk)
            : nullptr;

  const int lane = t & 63, wave = t >> 6;
  const int wr = wave >> 1, wc = wave & 1;
  const int fr = lane & 15;
  const int fq = lane >> 4;

  f32x4 acc[4][4] = {};

  for (int k0 = 0; k0 < K; k0 += 32) {
    s16x8 ah0, ah1, al0, al1, bh0, bh1, bl0, bl1;
    if (ABF) {
      ah0 = *(const s16x8*)(aptrH + k0);
      ah1 = *(const s16x8*)(aptrH + k0 + 8);
      if (SPLIT) {
        al0 = *(const s16x8*)(aptrL + k0);
        al1 = *(const s16x8*)(aptrL + k0 + 8);
      }
    } else {
      float4 a0 = *(const float4*)(aptrF + k0);
      float4 a1 = *(const float4*)(aptrF + k0 + 4);
      float4 a2 = *(const float4*)(aptrF + k0 + 8);
      float4 a3 = *(const float4*)(aptrF + k0 + 12);
      cvt8(a0, a1, ah0, al0, SPLIT);
      cvt8(a2, a3, ah1, al1, SPLIT);
    }
    bh0 = *(const s16x8*)(bptrH + k0);
    bh1 = *(const s16x8*)(bptrH + k0 + 8);
    if (SPLIT) {
      bl0 = *(const s16x8*)(bptrL + k0);
      bl1 = *(const s16x8*)(bptrL + k0 + 8);
    }

    __syncthreads();
    *(s16x8*)&Ah[sr * 40 + sk] = ah0;
    *(s16x8*)&Ah[sr * 40 + sk + 8] = ah1;
    *(s16x8*)&Bh[sr * 40 + sk] = bh0;
    *(s16x8*)&Bh[sr * 40 + sk + 8] = bh1;
    if (SPLIT) {
      *(s16x8*)&Al[sr * 40 + sk] = al0;
      *(s16x8*)&Al[sr * 40 + sk + 8] = al1;
      *(s16x8*)&Bl[sr * 40 + sk] = bl0;
      *(s16x8*)&Bl[sr * 40 + sk + 8] = bl1;
    }
    __syncthreads();

    s16x8 afh[4], afl[4];
#pragma unroll
    for (int m = 0; m < 4; ++m) {
      int ro = (wr * 64 + m * 16 + fr) * 40 + fq * 8;
      afh[m] = *(const s16x8*)&Ah[ro];
      if (SPLIT) afl[m] = *(const s16x8*)&Al[ro];
    }
#pragma unroll
    for (int n = 0; n < 4; ++n) {
      int ro = (wc * 64 + n * 16 + fr) * 40 + fq * 8;
      s16x8 bfh = *(const s16x8*)&Bh[ro];
      s16x8 bfl;
      if (SPLIT) bfl = *(const s16x8*)&Bl[ro];
#pragma unroll
      for (int m = 0; m < 4; ++m) {
        acc[m][n] =
            __builtin_amdgcn_mfma_f32_16x16x32_bf16(afh[m], bfh, acc[m][n], 0, 0, 0);
        if (SPLIT) {
          acc[m][n] = __builtin_amdgcn_mfma_f32_16x16x32_bf16(afh[m], bfl,
                                                              acc[m][n], 0, 0, 0);
          acc[m][n] = __builtin_amdgcn_mfma_f32_16x16x32_bf16(afl[m], bfh,
                                                              acc[m][n], 0, 0, 0);
        }
      }
    }
  }

  float* Cb = C + (size_t)z * cStride;
#pragma unroll
  for (int m = 0; m < 4; ++m) {
#pragma unroll
    for (int n = 0; n < 4; ++n) {
#pragma unroll
      for (int r = 0; r < 4; ++r) {
        int rg = row0 + wr * 64 + m * 16 + fq * 4 + r;
        int cg = col0 + wc * 64 + n * 16 + fr;
        float v = acc[m][n][r] * outscale;
        if (biasu) v += biasu[cg];
        if (act) v = v > 0.f ? v : 0.01f * v;
        Cb[(size_t)rg * N + cg] = v;
        if (WOUT) {
          short hh = f2bf(v);
          Chi[(size_t)rg * N + cg] = hh;
          Clo[(size_t)rg * N + cg] = f2bf(v - bf2f(hh));
        }
      }
    }
  }
}

// -------- top-k: full bitonic sort of 1024 (desc, tie -> smaller idx) -----
__global__ __launch_bounds__(512) void topk_kernel(
    const float* __restrict__ logits, float* __restrict__ tw,
    int* __restrict__ ti) {
  const int row = blockIdx.x;
  __shared__ float v[NTOK];
  __shared__ int id[NTOK];
  const int t = threadIdx.x;
  for (int i = t; i < NTOK; i += 512) {
    v[i] = logits[(size_t)row * NTOK + i];
    id[i] = i;
  }
  __syncthreads();
  for (int k = 2; k <= NTOK; k <<= 1) {
    for (int j = k >> 1; j > 0; j >>= 1) {
      int i = ((t & ~(j - 1)) << 1) | (t & (j - 1));
      int p = i | j;
      float va = v[i], vb = v[p];
      int ia = id[i], ib = id[p];
      bool aFirst = (va > vb) || (va == vb && ia < ib);
      bool desc = ((i & k) == 0);
      if (desc ? !aFirst : aFirst) {
        v[i] = vb;
        v[p] = va;
        id[i] = ib;
        id[p] = ia;
      }
      __syncthreads();
    }
  }
  if (t < KSEL) {
    tw[(size_t)row * KSEL + t] = v[t];
    ti[(size_t)row * KSEL + t] = id[t];
  }
}

// -------- agg1: gated ka weights (2 blocks/row, XCD-batch affinity) ------
__global__ __launch_bounds__(256) void agg1(const float* __restrict__ e_h,
                                            const float* __restrict__ e_t,
                                            const float* __restrict__ tw,
                                            const int* __restrict__ ti,
                                            float* __restrict__ kaw_raw) {
  const int bid = blockIdx.x;
  const int xcd = bid & 7, slot = bid >> 3;
  const int batch = xcd >> 1;
  const int u = ((xcd & 1) << 8) | slot;
  const int row = batch * 256 + (u >> 1);
  const int half = u & 1;
  const int t = threadIdx.x, lane = t & 63, wave = t >> 6;
  __shared__ float p[KSEL];
  __shared__ int idxs[KSEL];
  __shared__ float red[2];

  if (t < KSEL) {
    p[t] = tw[(size_t)row * KSEL + t];
    idxs[t] = ti[(size_t)row * KSEL + t];
  }
  __syncthreads();
  if (wave == 0) {
    float m = wmaxr(fmaxf(p[lane], p[lane + 64]));
    if (!lane) red[0] = m;
  }
  __syncthreads();
  if (t < KSEL) p[t] = __expf(p[t] - red[0]);
  __syncthreads();
  if (wave == 0) {
    float s = wsum(p[lane] + p[lane + 64]);
    if (!lane) red[1] = s;
  }
  __syncthreads();
  if (t < KSEL) p[t] *= (1.f / red[1]);
  __syncthreads();

  float ehr[12];
  {
    const float* ehrow = e_h + (size_t)row * DDIM;
#pragma unroll
    for (int c = 0; c < 3; ++c) {
      float4 v = *(const float4*)(ehrow + 4 * lane + 256 * c);
      ehr[4 * c + 0] = v.x;
      ehr[4 * c + 1] = v.y;
      ehr[4 * c + 2] = v.z;
      ehr[4 * c + 3] = v.w;
    }
  }
  const float* etb = e_t + (size_t)batch * NTOK * DDIM;

  for (int i = 0; i < 16; ++i) {
    int j = half * 64 + wave * 16 + i;
    float pj = p[j];
    float a = 4.f - 2.f * pj, b2 = 2.f * pj;
    const float* nb = etb + (size_t)idxs[j] * DDIM;
    float partial = 0.f;
#pragma unroll
    for (int c = 0; c < 3; ++c) {
      float4 nv = *(const float4*)(nb + 4 * lane + 256 * c);
      float nq[4] = {nv.x, nv.y, nv.z, nv.w};
#pragma unroll
      for (int q = 0; q < 4; ++q) {
        // tanh(y) = 1 - 2/(exp(2y)+1), 2y folded into gate FMA
        float y2 = fmaf(a, ehr[4 * c + q], b2 * nq[q]);
        float ex = __expf(y2);
        float g = fmaf(-2.f, __builtin_amdgcn_rcpf(1.f + ex), 1.f);
        partial = fmaf(nq[q], g, partial);
      }
    }
    partial = wsum(partial);
    if (!lane) kaw_raw[(size_t)row * KSEL + j] = partial;
  }
}

// -------- agg2: ka softmax + weighted sum -> bf16 lin inputs -------------
__global__ __launch_bounds__(192) void agg2(
    const float* __restrict__ e_h, const float* __restrict__ e_t,
    const float* __restrict__ cls, const float* __restrict__ kaw_raw,
    const int* __restrict__ ti, short* __restrict__ inbf) {
  const int bid = blockIdx.x;
  const int xcd = bid & 7, slot = bid >> 3;
  const int batch = xcd >> 1;
  const int row = batch * 256 + (xcd & 1) * 128 + slot;
  const int t = threadIdx.x, lane = t & 63, wave = t >> 6;
  __shared__ float kp[KSEL];
  __shared__ int idxs[KSEL];
  __shared__ float red[2];

  if (t < KSEL) {
    kp[t] = kaw_raw[(size_t)row * KSEL + t];
    idxs[t] = ti[(size_t)row * KSEL + t];
  }
  __syncthreads();
  if (wave == 0) {
    float m = wmaxr(fmaxf(kp[lane], kp[lane + 64]));
    if (!lane) red[0] = m;
  }
  __syncthreads();
  if (t < KSEL) kp[t] = __expf(kp[t] - red[0]);
  __syncthreads();
  if (wave == 0) {
    float s = wsum(kp[lane] + kp[lane + 64]);
    if (!lane) red[1] = s;
  }
  __syncthreads();
  if (t < KSEL) kp[t] *= (1.f / red[1]);
  __syncthreads();

  const size_t o = (size_t)row * DDIM + 4 * t;
  float4 eh4 = *(const float4*)(e_h + o);
  float4 cl4 = *(const float4*)(cls + o);
  const float* etb = e_t + (size_t)batch * NTOK * DDIM;

  float ax = 0.f, ay = 0.f, az = 0.f, aw = 0.f;
#pragma unroll 8
  for (int j = 0; j < KSEL; ++j) {
    float pr = kp[j];
    float4 nb = *(const float4*)(etb + (size_t)idxs[j] * DDIM + 4 * t);
    ax = fmaf(pr, nb.x, ax);
    ay = fmaf(pr, nb.y, ay);
    az = fmaf(pr, nb.z, az);
    aw = fmaf(pr, nb.w, aw);
  }

  short4 sv, bv;
  sv.x = f2bf((eh4.x + ax) * 0.1f + cl4.x);
  sv.y = f2bf((eh4.y + ay) * 0.1f + cl4.y);
  sv.z = f2bf((eh4.z + az) * 0.1f + cl4.z);
  sv.w = f2bf((eh4.w + aw) * 0.1f + cl4.w);
  bv.x = f2bf((eh4.x * ax) * 0.1f + cl4.x);
  bv.y = f2bf((eh4.y * ay) * 0.1f + cl4.y);
  bv.z = f2bf((eh4.z * az) * 0.1f + cl4.z);
  bv.w = f2bf((eh4.w * aw) * 0.1f + cl4.w);
  *(short4*)&inbf[o] = sv;
  *(short4*)&inbf[(size_t)(NBATCH * NCLS) * DDIM + o] = bv;
}

// -------- layernorm over D=768 on (embA[row] + embB[row]) --------
__global__ __launch_bounds__(256) void ln_kernel(const float* __restrict__ embA,
                                                 const float* __restrict__ embB,
                                                 const float* __restrict__ lw,
                                                 const float* __restrict__ lb,
                                                 float* __restrict__ out) {
  const int row = blockIdx.x;
  const int t = threadIdx.x;
  const int lane = t & 63, wave = t >> 6;
  __shared__ float red[4];
  __shared__ float bs[2];
  float e[3];
#pragma unroll
  for (int c = 0; c < 3; ++c) {
    size_t o = (size_t)row * DDIM + t + 256 * c;
    e[c] = embA[o] + embB[o];
  }
  float s = e[0] + e[1] + e[2];
  s = wsum(s);
  if (lane == 0) red[wave] = s;
  __syncthreads();
  if (t == 0) bs[0] = (red[0] + red[1] + red[2] + red[3]) * (1.f / DDIM);
  __syncthreads();
  float mu = bs[0];
  float q = 0.f;
#pragma unroll
  for (int c = 0; c < 3; ++c) {
    float d = e[c] - mu;
    q = fmaf(d, d, q);
  }
  q = wsum(q);
  if (lane == 0) red[wave] = q;
  __syncthreads();
  if (t == 0) bs[1] = (red[0] + red[1] + red[2] + red[3]) * (1.f / DDIM);
  __syncthreads();
  float rstd = rsqrtf(bs[1] + 1e-5f);
#pragma unroll
  for (int c = 0; c < 3; ++c) {
    int d = t + 256 * c;
    out[(size_t)row * DDIM + d] = (e[c] - mu) * rstd * lw[d] + lb[d];
  }
}

// ---------------- launch ----------------
extern "C" void kernel_launch(void* const* d_in, const int* in_sizes, int n_in,
                              void* d_out, int out_size, void* d_ws,
                              size_t ws_size, hipStream_t stream) {
  const float* cls = (const float*)d_in[0];
  const float* feats = (const float*)d_in[1];
  const float* Whw = (const float*)d_in[2];
  const float* Whb = (const float*)d_in[3];
  const float* Wtw = (const float*)d_in[4];
  const float* Wtb = (const float*)d_in[5];
  const float* l1w = (const float*)d_in[6];
  const float* l1b = (const float*)d_in[7];
  const float* l2w = (const float*)d_in[8];
  const float* l2b = (const float*)d_in[9];
  const float* lnw = (const float*)d_in[10];
  const float* lnb = (const float*)d_in[11];
  float* out = (float*)d_out;

  float* ws = (float*)d_ws;
  // layout (float units)
  float* e_h = ws;                          // 786432
  float* e_t = ws + 786432;                 // 3145728
  short* eh_hi = (short*)(ws + 3932160);    // 786432 shorts
  short* eh_lo = eh_hi + 786432;            // 786432 shorts (ends 4718592f)
  short* et_hi = (short*)(ws + 4718592);    // 3145728 shorts
  short* et_lo = et_hi + 3145728;           // (ends 7864320f)
  short* WhT_h = (short*)(ws + 7864320);    // 589824 shorts each
  short* WhT_l = WhT_h + 589824;
  short* WtT_h = WhT_h + 2 * 589824;
  short* WtT_l = WhT_h + 3 * 589824;        // (ends 9043968f)
  short* L1T = (short*)(ws + 9043968);      // 589824 shorts
  short* L2T = L1T + 589824;                // (ends 9633792f)
  float* logits = ws + 7864320;             // overlays WhT/WtT (dead by then)
  float* tw = ws + 9633792;                 // 131072
  int* ti = (int*)(ws + 9764864);           // 131072
  float* kaw = ws + 9895936;                // 131072
  short* inbf = (short*)(ws + 10027008);    // 2048*768 shorts (786432 f)
  float* linC = e_t;                        // overlays e_t (dead after agg2)
  (void)ws_size;
  (void)in_sizes;
  (void)n_in;
  (void)out_size;

  const float scale = 0.036084391824351615f;  // 1/sqrt(768)
  const int BIG = 1 << 30;
  dim3 blk(256);

  // weights -> transposed bf16 (hi/lo for Wh/Wt, plain for L1/L2)
  prep_weights<<<dim3(24, 24, 4), blk, 0, stream>>>(
      Whw, Wtw, l1w, l2w, WhT_h, WtT_h, L1T, L2T, WhT_l, WtT_l);
  // e_h = cls @ Wh + b (split; also emit bf16 hi/lo)
  gemm_nt<1, 0, 1><<<dim3(6, 8, 1), blk, 0, stream>>>(
      cls, nullptr, nullptr, nullptr, WhT_h, WhT_l, nullptr, Whb, nullptr, e_h,
      eh_hi, eh_lo, DDIM, DDIM, 0, 0, BIG, 1.f, 0, 0, 0);
  // e_t = concat(cls,feats) @ Wt + b (split; also emit bf16 hi/lo)
  gemm_nt<1, 0, 1><<<dim3(6, 32, 1), blk, 0, stream>>>(
      cls, feats, nullptr, nullptr, WtT_h, WtT_l, nullptr, Wtb, nullptr, e_t,
      et_hi, et_lo, DDIM, DDIM, 1, 0, BIG, 1.f, 0, 0, 0);
  // logits[b] = scale * e_h[b] @ e_t[b]^T (pure bf16 staging)
  gemm_nt<1, 1, 0><<<dim3(8, 2, 4), blk, 0, stream>>>(
      nullptr, nullptr, eh_hi, eh_lo, et_hi, et_lo, nullptr, nullptr, nullptr,
      logits, nullptr, nullptr, NTOK, DDIM, 0, 0, BIG, scale,
      (long)NCLS * DDIM, (long)NTOK * DDIM, (long)NCLS * NTOK);
  // top-128 per row
  topk_kernel<<<dim3(NBATCH * NCLS), dim3(512), 0, stream>>>(logits, tw, ti);
  // agg1: gated ka weights (2048 blocks)
  agg1<<<dim3(2048), blk, 0, stream>>>(e_h, e_t, tw, ti, kaw);
  // agg2: softmax + weighted sum -> bf16 lin inputs
  agg2<<<dim3(1024), dim3(192), 0, stream>>>(e_h, e_t, cls, kaw, ti, inbf);
  // fused lin1/lin2 (bf16 A, bf16 B): rows<1024 -> l1, else l2
  gemm_nt<0, 1, 0><<<dim3(6, 16, 1), blk, 0, stream>>>(
      nullptr, nullptr, inbf, nullptr, L1T, nullptr, L2T, l1b, l2b, linC,
      nullptr, nullptr, DDIM, DDIM, 0, 1, 1024, 1.f, 0, 0, 0);
  // layernorm(sum_emb + bi_emb) -> out
  ln_kernel<<<dim3(NBATCH * NCLS), blk, 0, stream>>>(
      linC, linC + (size_t)(NBATCH * NCLS) * DDIM, lnw, lnb, out);
}

// Round 5
// 151.694 us; speedup vs baseline: 2.4419x; 1.6816x over previous
//
#include <hip/hip_runtime.h>
#include <hip/hip_bf16.h>
#include <math.h>

#define DDIM 768
#define NCLS 256
#define NFEAT 768
#define NTOK 1024
#define NBATCH 4
#define KSEL 128

typedef float f32x4 __attribute__((ext_vector_type(4)));
typedef short s16x8 __attribute__((ext_vector_type(8)));

// ---------------- helpers ----------------
__device__ __forceinline__ float wsum(float v) {
#pragma unroll
  for (int o = 32; o; o >>= 1) v += __shfl_down(v, o, 64);
  return v;
}
__device__ __forceinline__ float wmaxr(float v) {
#pragma unroll
  for (int o = 32; o; o >>= 1) v = fmaxf(v, __shfl_down(v, o, 64));
  return v;
}
__device__ __forceinline__ short f2bf(float f) {
  union { __hip_bfloat16 h; short s; } u;
  u.h = __float2bfloat16(f);
  return u.s;
}
__device__ __forceinline__ float bf2f(short s) {
  union { unsigned u; float f; } c;
  c.u = ((unsigned)(unsigned short)s) << 16;
  return c.f;
}
__device__ __forceinline__ void cvt8(float4 x, float4 y, s16x8& h, s16x8& l) {
  float v[8] = {x.x, x.y, x.z, x.w, y.x, y.y, y.z, y.w};
#pragma unroll
  for (int i = 0; i < 8; ++i) {
    short hh = f2bf(v[i]);
    h[i] = hh;
    l[i] = f2bf(v[i] - bf2f(hh));
  }
}

// -------- transpose + bf16-convert weights (z: 0=Wh split,1=Wt split,
//          2=L1 plain,3=L2 plain) --------
__global__ __launch_bounds__(256) void prep_weights(
    const float* __restrict__ w0, const float* __restrict__ w1,
    const float* __restrict__ w2, const float* __restrict__ w3,
    short* __restrict__ h0, short* __restrict__ h1, short* __restrict__ h2,
    short* __restrict__ h3, short* __restrict__ l0, short* __restrict__ l1) {
  __shared__ float tile[32][33];
  const int z = blockIdx.z;
  const float* s = z == 0 ? w0 : z == 1 ? w1 : z == 2 ? w2 : w3;
  short* dh = z == 0 ? h0 : z == 1 ? h1 : z == 2 ? h2 : h3;
  short* dl = z == 0 ? l0 : z == 1 ? l1 : nullptr;
  const int tx = threadIdx.x & 31, ty0 = threadIdx.x >> 5;
  const int r0 = blockIdx.y * 32, c0 = blockIdx.x * 32;
#pragma unroll
  for (int i = 0; i < 4; ++i) {
    int ty = ty0 + i * 8;
    tile[ty][tx] = s[(size_t)(r0 + ty) * DDIM + c0 + tx];
  }
  __syncthreads();
#pragma unroll
  for (int i = 0; i < 4; ++i) {
    int ty = ty0 + i * 8;
    float v = tile[tx][ty];
    short hh = f2bf(v);
    dh[(size_t)(c0 + ty) * DDIM + r0 + tx] = hh;
    if (dl) dl[(size_t)(c0 + ty) * DDIM + r0 + tx] = f2bf(v - bf2f(hh));
  }
}

// -------- front GEMM (fused e_h | e_t), 64x64 tiles, split-bf16 ----------
// rows 0..1023 -> e_h = cls @ WhT^T + Whb ; rows 1024..5119 -> e_t rows of
// concat(cls,feats)@WtT^T + Wtb. Emits fp32 + bf16 hi/lo.
__global__ __launch_bounds__(256) void gemm_front(
    const float* __restrict__ cls, const float* __restrict__ feats,
    const short* __restrict__ WhT_h, const short* __restrict__ WhT_l,
    const float* __restrict__ Whb, const short* __restrict__ WtT_h,
    const short* __restrict__ WtT_l, const float* __restrict__ Wtb,
    float* __restrict__ e_h, short* __restrict__ eh_hi,
    short* __restrict__ eh_lo, float* __restrict__ e_t,
    short* __restrict__ et_hi, short* __restrict__ et_lo) {
  __shared__ short Ah[64 * 40], Bh[64 * 40], Al[64 * 40], Bl[64 * 40];
  const int t = threadIdx.x;
  const int row0 = blockIdx.y * 64;
  const int col0 = blockIdx.x * 64;
  const bool head = row0 < 1024;
  const int sr = t >> 2, sk = (t & 3) * 8;

  const float* aptr;
  {
    int gr = row0 + sr;
    if (head) {
      aptr = cls + (size_t)gr * DDIM;
    } else {
      int r2 = gr - 1024, b = r2 >> 10, rr = r2 & 1023;
      aptr = (rr < NCLS) ? (cls + ((size_t)b * NCLS + rr) * DDIM)
                         : (feats + ((size_t)b * NFEAT + (rr - NCLS)) * DDIM);
    }
    aptr += sk;
  }
  const short* bph = (head ? WhT_h : WtT_h) + (size_t)(col0 + sr) * DDIM + sk;
  const short* bpl = (head ? WhT_l : WtT_l) + (size_t)(col0 + sr) * DDIM + sk;
  const float* biasu = head ? Whb : Wtb;

  const int lane = t & 63, wave = t >> 6;
  const int wr = wave >> 1, wc = wave & 1;
  const int fr = lane & 15, fq = lane >> 4;

  f32x4 acc[2][2] = {};
  for (int k0 = 0; k0 < DDIM; k0 += 32) {
    float4 a0 = *(const float4*)(aptr + k0);
    float4 a1 = *(const float4*)(aptr + k0 + 4);
    s16x8 ah, al;
    cvt8(a0, a1, ah, al);
    s16x8 bh = *(const s16x8*)(bph + k0);
    s16x8 bl = *(const s16x8*)(bpl + k0);
    __syncthreads();
    *(s16x8*)&Ah[sr * 40 + sk] = ah;
    *(s16x8*)&Al[sr * 40 + sk] = al;
    *(s16x8*)&Bh[sr * 40 + sk] = bh;
    *(s16x8*)&Bl[sr * 40 + sk] = bl;
    __syncthreads();
#pragma unroll
    for (int n = 0; n < 2; ++n) {
      int bo = (wc * 32 + n * 16 + fr) * 40 + fq * 8;
      s16x8 bfh = *(const s16x8*)&Bh[bo];
      s16x8 bfl = *(const s16x8*)&Bl[bo];
#pragma unroll
      for (int m = 0; m < 2; ++m) {
        int ao = (wr * 32 + m * 16 + fr) * 40 + fq * 8;
        s16x8 afh = *(const s16x8*)&Ah[ao];
        s16x8 afl = *(const s16x8*)&Al[ao];
        acc[m][n] =
            __builtin_amdgcn_mfma_f32_16x16x32_bf16(afh, bfh, acc[m][n], 0, 0, 0);
        acc[m][n] =
            __builtin_amdgcn_mfma_f32_16x16x32_bf16(afh, bfl, acc[m][n], 0, 0, 0);
        acc[m][n] =
            __builtin_amdgcn_mfma_f32_16x16x32_bf16(afl, bfh, acc[m][n], 0, 0, 0);
      }
    }
  }

  float* Cf = head ? e_h : e_t;
  short* Ch = head ? eh_hi : et_hi;
  short* Cl = head ? eh_lo : et_lo;
  const int rbase = head ? row0 : row0 - 1024;
#pragma unroll
  for (int m = 0; m < 2; ++m) {
#pragma unroll
    for (int n = 0; n < 2; ++n) {
#pragma unroll
      for (int r = 0; r < 4; ++r) {
        int rg = rbase + wr * 32 + m * 16 + fq * 4 + r;
        int cg = col0 + wc * 32 + n * 16 + fr;
        float v = acc[m][n][r] + biasu[cg];
        size_t o = (size_t)rg * DDIM + cg;
        Cf[o] = v;
        short hh = f2bf(v);
        Ch[o] = hh;
        Cl[o] = f2bf(v - bf2f(hh));
      }
    }
  }
}

// -------- logits GEMM: scale * e_h[b] @ e_t[b]^T, 64x64 tiles, split -----
__global__ __launch_bounds__(256) void gemm_logits(
    const short* __restrict__ eh_hi, const short* __restrict__ eh_lo,
    const short* __restrict__ et_hi, const short* __restrict__ et_lo,
    float* __restrict__ logits, float scale) {
  __shared__ short Ah[64 * 40], Bh[64 * 40], Al[64 * 40], Bl[64 * 40];
  const int t = threadIdx.x;
  const int batch = blockIdx.z;
  const int row0 = blockIdx.y * 64, col0 = blockIdx.x * 64;
  const int sr = t >> 2, sk = (t & 3) * 8;
  const size_t aoff = ((size_t)batch * NCLS + row0 + sr) * DDIM + sk;
  const size_t boff = ((size_t)batch * NTOK + col0 + sr) * DDIM + sk;
  const int lane = t & 63, wave = t >> 6;
  const int wr = wave >> 1, wc = wave & 1;
  const int fr = lane & 15, fq = lane >> 4;

  f32x4 acc[2][2] = {};
  for (int k0 = 0; k0 < DDIM; k0 += 32) {
    s16x8 ah = *(const s16x8*)(eh_hi + aoff + k0);
    s16x8 al = *(const s16x8*)(eh_lo + aoff + k0);
    s16x8 bh = *(const s16x8*)(et_hi + boff + k0);
    s16x8 bl = *(const s16x8*)(et_lo + boff + k0);
    __syncthreads();
    *(s16x8*)&Ah[sr * 40 + sk] = ah;
    *(s16x8*)&Al[sr * 40 + sk] = al;
    *(s16x8*)&Bh[sr * 40 + sk] = bh;
    *(s16x8*)&Bl[sr * 40 + sk] = bl;
    __syncthreads();
#pragma unroll
    for (int n = 0; n < 2; ++n) {
      int bo = (wc * 32 + n * 16 + fr) * 40 + fq * 8;
      s16x8 bfh = *(const s16x8*)&Bh[bo];
      s16x8 bfl = *(const s16x8*)&Bl[bo];
#pragma unroll
      for (int m = 0; m < 2; ++m) {
        int ao = (wr * 32 + m * 16 + fr) * 40 + fq * 8;
        s16x8 afh = *(const s16x8*)&Ah[ao];
        s16x8 afl = *(const s16x8*)&Al[ao];
        acc[m][n] =
            __builtin_amdgcn_mfma_f32_16x16x32_bf16(afh, bfh, acc[m][n], 0, 0, 0);
        acc[m][n] =
            __builtin_amdgcn_mfma_f32_16x16x32_bf16(afh, bfl, acc[m][n], 0, 0, 0);
        acc[m][n] =
            __builtin_amdgcn_mfma_f32_16x16x32_bf16(afl, bfh, acc[m][n], 0, 0, 0);
      }
    }
  }

  float* Cb = logits + (size_t)batch * NCLS * NTOK;
#pragma unroll
  for (int m = 0; m < 2; ++m)
#pragma unroll
    for (int n = 0; n < 2; ++n)
#pragma unroll
      for (int r = 0; r < 4; ++r) {
        int rg = row0 + wr * 32 + m * 16 + fq * 4 + r;
        int cg = col0 + wc * 32 + n * 16 + fr;
        Cb[(size_t)rg * NTOK + cg] = scale * acc[m][n][r];
      }
}

// -------- lin GEMM (fused lin1/lin2), 64x64, plain bf16, leaky ----------
__global__ __launch_bounds__(256) void gemm_lin(
    const short* __restrict__ inbf, const short* __restrict__ L1T,
    const short* __restrict__ L2T, const float* __restrict__ b1,
    const float* __restrict__ b2, float* __restrict__ C) {
  __shared__ short Ah[64 * 40], Bh[64 * 40];
  const int t = threadIdx.x;
  const int row0 = blockIdx.y * 64, col0 = blockIdx.x * 64;
  const bool second = row0 >= 1024;
  const int sr = t >> 2, sk = (t & 3) * 8;
  const short* aptr = inbf + (size_t)(row0 + sr) * DDIM + sk;
  const short* bptr = (second ? L2T : L1T) + (size_t)(col0 + sr) * DDIM + sk;
  const float* biasu = second ? b2 : b1;
  const int lane = t & 63, wave = t >> 6;
  const int wr = wave >> 1, wc = wave & 1;
  const int fr = lane & 15, fq = lane >> 4;

  f32x4 acc[2][2] = {};
  for (int k0 = 0; k0 < DDIM; k0 += 32) {
    s16x8 ah = *(const s16x8*)(aptr + k0);
    s16x8 bh = *(const s16x8*)(bptr + k0);
    __syncthreads();
    *(s16x8*)&Ah[sr * 40 + sk] = ah;
    *(s16x8*)&Bh[sr * 40 + sk] = bh;
    __syncthreads();
#pragma unroll
    for (int n = 0; n < 2; ++n) {
      int bo = (wc * 32 + n * 16 + fr) * 40 + fq * 8;
      s16x8 bfh = *(const s16x8*)&Bh[bo];
#pragma unroll
      for (int m = 0; m < 2; ++m) {
        int ao = (wr * 32 + m * 16 + fr) * 40 + fq * 8;
        s16x8 afh = *(const s16x8*)&Ah[ao];
        acc[m][n] =
            __builtin_amdgcn_mfma_f32_16x16x32_bf16(afh, bfh, acc[m][n], 0, 0, 0);
      }
    }
  }
#pragma unroll
  for (int m = 0; m < 2; ++m)
#pragma unroll
    for (int n = 0; n < 2; ++n)
#pragma unroll
      for (int r = 0; r < 4; ++r) {
        int rg = row0 + wr * 32 + m * 16 + fq * 4 + r;
        int cg = col0 + wc * 32 + n * 16 + fr;
        float v = acc[m][n][r] + biasu[cg];
        v = v > 0.f ? v : 0.01f * v;
        C[(size_t)rg * DDIM + cg] = v;
      }
}

// -------- top-k: full bitonic sort of 1024 (desc, tie -> smaller idx) -----
__global__ __launch_bounds__(512) void topk_kernel(
    const float* __restrict__ logits, float* __restrict__ tw,
    int* __restrict__ ti) {
  const int row = blockIdx.x;
  __shared__ float v[NTOK];
  __shared__ int id[NTOK];
  const int t = threadIdx.x;
  for (int i = t; i < NTOK; i += 512) {
    v[i] = logits[(size_t)row * NTOK + i];
    id[i] = i;
  }
  __syncthreads();
  for (int k = 2; k <= NTOK; k <<= 1) {
    for (int j = k >> 1; j > 0; j >>= 1) {
      int i = ((t & ~(j - 1)) << 1) | (t & (j - 1));
      int p = i | j;
      float va = v[i], vb = v[p];
      int ia = id[i], ib = id[p];
      bool aFirst = (va > vb) || (va == vb && ia < ib);
      bool desc = ((i & k) == 0);
      if (desc ? !aFirst : aFirst) {
        v[i] = vb;
        v[p] = va;
        id[i] = ib;
        id[p] = ia;
      }
      __syncthreads();
    }
  }
  if (t < KSEL) {
    tw[(size_t)row * KSEL + t] = v[t];
    ti[(size_t)row * KSEL + t] = id[t];
  }
}

// -------- agg1: gated ka weights (2 blocks/row, XCD-batch affinity) ------
__global__ __launch_bounds__(256) void agg1(const float* __restrict__ e_h,
                                            const float* __restrict__ e_t,
                                            const float* __restrict__ tw,
                                            const int* __restrict__ ti,
                                            float* __restrict__ kaw_raw) {
  const int bid = blockIdx.x;
  const int xcd = bid & 7, slot = bid >> 3;
  const int batch = xcd >> 1;
  const int u = ((xcd & 1) << 8) | slot;
  const int row = batch * 256 + (u >> 1);
  const int half = u & 1;
  const int t = threadIdx.x, lane = t & 63, wave = t >> 6;
  __shared__ float p[KSEL];
  __shared__ int idxs[KSEL];
  __shared__ float red[2];

  if (t < KSEL) {
    p[t] = tw[(size_t)row * KSEL + t];
    idxs[t] = ti[(size_t)row * KSEL + t];
  }
  __syncthreads();
  if (wave == 0) {
    float m = wmaxr(fmaxf(p[lane], p[lane + 64]));
    if (!lane) red[0] = m;
  }
  __syncthreads();
  if (t < KSEL) p[t] = __expf(p[t] - red[0]);
  __syncthreads();
  if (wave == 0) {
    float s = wsum(p[lane] + p[lane + 64]);
    if (!lane) red[1] = s;
  }
  __syncthreads();
  if (t < KSEL) p[t] *= (1.f / red[1]);
  __syncthreads();

  float ehr[12];
  {
    const float* ehrow = e_h + (size_t)row * DDIM;
#pragma unroll
    for (int c = 0; c < 3; ++c) {
      float4 v = *(const float4*)(ehrow + 4 * lane + 256 * c);
      ehr[4 * c + 0] = v.x;
      ehr[4 * c + 1] = v.y;
      ehr[4 * c + 2] = v.z;
      ehr[4 * c + 3] = v.w;
    }
  }
  const float* etb = e_t + (size_t)batch * NTOK * DDIM;

  for (int i = 0; i < 16; ++i) {
    int j = half * 64 + wave * 16 + i;
    float pj = p[j];
    float a = 4.f - 2.f * pj, b2 = 2.f * pj;
    const float* nb = etb + (size_t)idxs[j] * DDIM;
    float partial = 0.f;
#pragma unroll
    for (int c = 0; c < 3; ++c) {
      float4 nv = *(const float4*)(nb + 4 * lane + 256 * c);
      float nq[4] = {nv.x, nv.y, nv.z, nv.w};
#pragma unroll
      for (int q = 0; q < 4; ++q) {
        float y2 = fmaf(a, ehr[4 * c + q], b2 * nq[q]);
        float ex = __expf(y2);
        float g = fmaf(-2.f, __builtin_amdgcn_rcpf(1.f + ex), 1.f);
        partial = fmaf(nq[q], g, partial);
      }
    }
    partial = wsum(partial);
    if (!lane) kaw_raw[(size_t)row * KSEL + j] = partial;
  }
}

// -------- agg2: ka softmax + weighted sum -> bf16 lin inputs -------------
__global__ __launch_bounds__(192) void agg2(
    const float* __restrict__ e_h, const float* __restrict__ e_t,
    const float* __restrict__ cls, const float* __restrict__ kaw_raw,
    const int* __restrict__ ti, short* __restrict__ inbf) {
  const int bid = blockIdx.x;
  const int xcd = bid & 7, slot = bid >> 3;
  const int batch = xcd >> 1;
  const int row = batch * 256 + (xcd & 1) * 128 + slot;
  const int t = threadIdx.x, lane = t & 63, wave = t >> 6;
  __shared__ float kp[KSEL];
  __shared__ int idxs[KSEL];
  __shared__ float red[2];

  if (t < KSEL) {
    kp[t] = kaw_raw[(size_t)row * KSEL + t];
    idxs[t] = ti[(size_t)row * KSEL + t];
  }
  __syncthreads();
  if (wave == 0) {
    float m = wmaxr(fmaxf(kp[lane], kp[lane + 64]));
    if (!lane) red[0] = m;
  }
  __syncthreads();
  if (t < KSEL) kp[t] = __expf(kp[t] - red[0]);
  __syncthreads();
  if (wave == 0) {
    float s = wsum(kp[lane] + kp[lane + 64]);
    if (!lane) red[1] = s;
  }
  __syncthreads();
  if (t < KSEL) kp[t] *= (1.f / red[1]);
  __syncthreads();

  const size_t o = (size_t)row * DDIM + 4 * t;
  float4 eh4 = *(const float4*)(e_h + o);
  float4 cl4 = *(const float4*)(cls + o);
  const float* etb = e_t + (size_t)batch * NTOK * DDIM;

  float ax = 0.f, ay = 0.f, az = 0.f, aw = 0.f;
#pragma unroll 8
  for (int j = 0; j < KSEL; ++j) {
    float pr = kp[j];
    float4 nb = *(const float4*)(etb + (size_t)idxs[j] * DDIM + 4 * t);
    ax = fmaf(pr, nb.x, ax);
    ay = fmaf(pr, nb.y, ay);
    az = fmaf(pr, nb.z, az);
    aw = fmaf(pr, nb.w, aw);
  }

  short4 sv, bv;
  sv.x = f2bf((eh4.x + ax) * 0.1f + cl4.x);
  sv.y = f2bf((eh4.y + ay) * 0.1f + cl4.y);
  sv.z = f2bf((eh4.z + az) * 0.1f + cl4.z);
  sv.w = f2bf((eh4.w + aw) * 0.1f + cl4.w);
  bv.x = f2bf((eh4.x * ax) * 0.1f + cl4.x);
  bv.y = f2bf((eh4.y * ay) * 0.1f + cl4.y);
  bv.z = f2bf((eh4.z * az) * 0.1f + cl4.z);
  bv.w = f2bf((eh4.w * aw) * 0.1f + cl4.w);
  *(short4*)&inbf[o] = sv;
  *(short4*)&inbf[(size_t)(NBATCH * NCLS) * DDIM + o] = bv;
}

// -------- layernorm over D=768 on (embA[row] + embB[row]) --------
__global__ __launch_bounds__(256) void ln_kernel(const float* __restrict__ embA,
                                                 const float* __restrict__ embB,
                                                 const float* __restrict__ lw,
                                                 const float* __restrict__ lb,
                                                 float* __restrict__ out) {
  const int row = blockIdx.x;
  const int t = threadIdx.x;
  const int lane = t & 63, wave = t >> 6;
  __shared__ float red[4];
  __shared__ float bs[2];
  float e[3];
#pragma unroll
  for (int c = 0; c < 3; ++c) {
    size_t o = (size_t)row * DDIM + t + 256 * c;
    e[c] = embA[o] + embB[o];
  }
  float s = e[0] + e[1] + e[2];
  s = wsum(s);
  if (lane == 0) red[wave] = s;
  __syncthreads();
  if (t == 0) bs[0] = (red[0] + red[1] + red[2] + red[3]) * (1.f / DDIM);
  __syncthreads();
  float mu = bs[0];
  float q = 0.f;
#pragma unroll
  for (int c = 0; c < 3; ++c) {
    float d = e[c] - mu;
    q = fmaf(d, d, q);
  }
  q = wsum(q);
  if (lane == 0) red[wave] = q;
  __syncthreads();
  if (t == 0) bs[1] = (red[0] + red[1] + red[2] + red[3]) * (1.f / DDIM);
  __syncthreads();
  float rstd = rsqrtf(bs[1] + 1e-5f);
#pragma unroll
  for (int c = 0; c < 3; ++c) {
    int d = t + 256 * c;
    out[(size_t)row * DDIM + d] = (e[c] - mu) * rstd * lw[d] + lb[d];
  }
}

// ---------------- launch ----------------
extern "C" void kernel_launch(void* const* d_in, const int* in_sizes, int n_in,
                              void* d_out, int out_size, void* d_ws,
                              size_t ws_size, hipStream_t stream) {
  const float* cls = (const float*)d_in[0];
  const float* feats = (const float*)d_in[1];
  const float* Whw = (const float*)d_in[2];
  const float* Whb = (const float*)d_in[3];
  const float* Wtw = (const float*)d_in[4];
  const float* Wtb = (const float*)d_in[5];
  const float* l1w = (const float*)d_in[6];
  const float* l1b = (const float*)d_in[7];
  const float* l2w = (const float*)d_in[8];
  const float* l2b = (const float*)d_in[9];
  const float* lnw = (const float*)d_in[10];
  const float* lnb = (const float*)d_in[11];
  float* out = (float*)d_out;

  float* ws = (float*)d_ws;
  // layout (float units)
  float* e_h = ws;                          // 786432
  float* e_t = ws + 786432;                 // 3145728
  short* eh_hi = (short*)(ws + 3932160);    // 786432 shorts
  short* eh_lo = eh_hi + 786432;            // (ends 4718592f)
  short* et_hi = (short*)(ws + 4718592);    // 3145728 shorts
  short* et_lo = et_hi + 3145728;           // (ends 7864320f)
  short* WhT_h = (short*)(ws + 7864320);    // 589824 shorts each
  short* WhT_l = WhT_h + 589824;
  short* WtT_h = WhT_h + 2 * 589824;
  short* WtT_l = WhT_h + 3 * 589824;        // (ends 9043968f)
  short* L1T = (short*)(ws + 9043968);      // 589824 shorts
  short* L2T = L1T + 589824;                // (ends 9633792f)
  float* logits = ws + 7864320;             // overlays WhT/WtT (dead by then)
  float* tw = ws + 9633792;                 // 131072
  int* ti = (int*)(ws + 9764864);           // 131072
  float* kaw = ws + 9895936;                // 131072
  short* inbf = (short*)(ws + 10027008);    // 2048*768 shorts (786432 f)
  float* linC = e_t;                        // overlays e_t (dead after agg2)
  (void)ws_size;
  (void)in_sizes;
  (void)n_in;
  (void)out_size;

  const float scale = 0.036084391824351615f;  // 1/sqrt(768)
  dim3 blk(256);

  // weights -> transposed bf16 (hi/lo for Wh/Wt, plain for L1/L2)
  prep_weights<<<dim3(24, 24, 4), blk, 0, stream>>>(
      Whw, Wtw, l1w, l2w, WhT_h, WtT_h, L1T, L2T, WhT_l, WtT_l);
  // fused e_h | e_t (960 blocks)
  gemm_front<<<dim3(12, 80), blk, 0, stream>>>(
      cls, feats, WhT_h, WhT_l, Whb, WtT_h, WtT_l, Wtb, e_h, eh_hi, eh_lo, e_t,
      et_hi, et_lo);
  // logits[b] = scale * e_h[b] @ e_t[b]^T (256 blocks)
  gemm_logits<<<dim3(16, 4, 4), blk, 0, stream>>>(eh_hi, eh_lo, et_hi, et_lo,
                                                  logits, scale);
  // top-128 per row
  topk_kernel<<<dim3(NBATCH * NCLS), dim3(512), 0, stream>>>(logits, tw, ti);
  // agg1: gated ka weights (2048 blocks)
  agg1<<<dim3(2048), blk, 0, stream>>>(e_h, e_t, tw, ti, kaw);
  // agg2: softmax + weighted sum -> bf16 lin inputs
  agg2<<<dim3(1024), dim3(192), 0, stream>>>(e_h, e_t, cls, kaw, ti, inbf);
  // fused lin1/lin2 (384 blocks): rows<1024 -> l1, else l2
  gemm_lin<<<dim3(12, 32), blk, 0, stream>>>(inbf, L1T, L2T, l1b, l2b, linC);
  // layernorm(sum_emb + bi_emb) -> out
  ln_kernel<<<dim3(NBATCH * NCLS), blk, 0, stream>>>(
      linC, linC + (size_t)(NBATCH * NCLS) * DDIM, lnw, lnb, out);
}

// Round 6
// 130.946 us; speedup vs baseline: 2.8288x; 1.1584x over previous
//
#include <hip/hip_runtime.h>
#include <hip/hip_bf16.h>
#include <math.h>

#define DDIM 768
#define NCLS 256
#define NFEAT 768
#define NTOK 1024
#define NBATCH 4
#define KSEL 128

typedef float f32x4 __attribute__((ext_vector_type(4)));
typedef short s16x8 __attribute__((ext_vector_type(8)));

// ---------------- helpers ----------------
__device__ __forceinline__ float wsum(float v) {
#pragma unroll
  for (int o = 32; o; o >>= 1) v += __shfl_down(v, o, 64);
  return v;
}
__device__ __forceinline__ float wmaxr(float v) {
#pragma unroll
  for (int o = 32; o; o >>= 1) v = fmaxf(v, __shfl_down(v, o, 64));
  return v;
}
__device__ __forceinline__ short f2bf(float f) {
  union { __hip_bfloat16 h; short s; } u;
  u.h = __float2bfloat16(f);
  return u.s;
}
__device__ __forceinline__ float bf2f(short s) {
  union { unsigned u; float f; } c;
  c.u = ((unsigned)(unsigned short)s) << 16;
  return c.f;
}
__device__ __forceinline__ void cvt8(float4 x, float4 y, s16x8& h, s16x8& l) {
  float v[8] = {x.x, x.y, x.z, x.w, y.x, y.y, y.z, y.w};
#pragma unroll
  for (int i = 0; i < 8; ++i) {
    short hh = f2bf(v[i]);
    h[i] = hh;
    l[i] = f2bf(v[i] - bf2f(hh));
  }
}

// -------- transpose + bf16-convert weights (z: 0=Wh split,1=Wt split,
//          2=L1 plain,3=L2 plain) --------
__global__ __launch_bounds__(256) void prep_weights(
    const float* __restrict__ w0, const float* __restrict__ w1,
    const float* __restrict__ w2, const float* __restrict__ w3,
    short* __restrict__ h0, short* __restrict__ h1, short* __restrict__ h2,
    short* __restrict__ h3, short* __restrict__ l0, short* __restrict__ l1) {
  __shared__ float tile[32][33];
  const int z = blockIdx.z;
  const float* s = z == 0 ? w0 : z == 1 ? w1 : z == 2 ? w2 : w3;
  short* dh = z == 0 ? h0 : z == 1 ? h1 : z == 2 ? h2 : h3;
  short* dl = z == 0 ? l0 : z == 1 ? l1 : nullptr;
  const int tx = threadIdx.x & 31, ty0 = threadIdx.x >> 5;
  const int r0 = blockIdx.y * 32, c0 = blockIdx.x * 32;
#pragma unroll
  for (int i = 0; i < 4; ++i) {
    int ty = ty0 + i * 8;
    tile[ty][tx] = s[(size_t)(r0 + ty) * DDIM + c0 + tx];
  }
  __syncthreads();
#pragma unroll
  for (int i = 0; i < 4; ++i) {
    int ty = ty0 + i * 8;
    float v = tile[tx][ty];
    short hh = f2bf(v);
    dh[(size_t)(c0 + ty) * DDIM + r0 + tx] = hh;
    if (dl) dl[(size_t)(c0 + ty) * DDIM + r0 + tx] = f2bf(v - bf2f(hh));
  }
}

// -------- front GEMM (fused e_h | e_t), 64x64 tiles, split-bf16,
//          XCD-chunked 1D grid (960 = 8 XCD x 120) --------
__global__ __launch_bounds__(256) void gemm_front(
    const float* __restrict__ cls, const float* __restrict__ feats,
    const short* __restrict__ WhT_h, const short* __restrict__ WhT_l,
    const float* __restrict__ Whb, const short* __restrict__ WtT_h,
    const short* __restrict__ WtT_l, const float* __restrict__ Wtb,
    float* __restrict__ e_h, short* __restrict__ eh_hi,
    short* __restrict__ eh_lo, float* __restrict__ e_t,
    short* __restrict__ et_hi, short* __restrict__ et_lo) {
  __shared__ short Ah[64 * 40], Bh[64 * 40], Al[64 * 40], Bl[64 * 40];
  const int bid = blockIdx.x;
  const int xcd = bid & 7, idx = bid >> 3;  // idx 0..119
  const int ytile = xcd * 10 + idx / 12;    // contiguous row strip per XCD
  const int xtile = idx % 12;
  const int t = threadIdx.x;
  const int row0 = ytile * 64;
  const int col0 = xtile * 64;
  const bool head = row0 < 1024;
  const int sr = t >> 2, sk = (t & 3) * 8;

  const float* aptr;
  {
    int gr = row0 + sr;
    if (head) {
      aptr = cls + (size_t)gr * DDIM;
    } else {
      int r2 = gr - 1024, b = r2 >> 10, rr = r2 & 1023;
      aptr = (rr < NCLS) ? (cls + ((size_t)b * NCLS + rr) * DDIM)
                         : (feats + ((size_t)b * NFEAT + (rr - NCLS)) * DDIM);
    }
    aptr += sk;
  }
  const short* bph = (head ? WhT_h : WtT_h) + (size_t)(col0 + sr) * DDIM + sk;
  const short* bpl = (head ? WhT_l : WtT_l) + (size_t)(col0 + sr) * DDIM + sk;
  const float* biasu = head ? Whb : Wtb;

  const int lane = t & 63, wave = t >> 6;
  const int wr = wave >> 1, wc = wave & 1;
  const int fr = lane & 15, fq = lane >> 4;

  f32x4 acc[2][2] = {};
  for (int k0 = 0; k0 < DDIM; k0 += 32) {
    float4 a0 = *(const float4*)(aptr + k0);
    float4 a1 = *(const float4*)(aptr + k0 + 4);
    s16x8 ah, al;
    cvt8(a0, a1, ah, al);
    s16x8 bh = *(const s16x8*)(bph + k0);
    s16x8 bl = *(const s16x8*)(bpl + k0);
    __syncthreads();
    *(s16x8*)&Ah[sr * 40 + sk] = ah;
    *(s16x8*)&Al[sr * 40 + sk] = al;
    *(s16x8*)&Bh[sr * 40 + sk] = bh;
    *(s16x8*)&Bl[sr * 40 + sk] = bl;
    __syncthreads();
#pragma unroll
    for (int n = 0; n < 2; ++n) {
      int bo = (wc * 32 + n * 16 + fr) * 40 + fq * 8;
      s16x8 bfh = *(const s16x8*)&Bh[bo];
      s16x8 bfl = *(const s16x8*)&Bl[bo];
#pragma unroll
      for (int m = 0; m < 2; ++m) {
        int ao = (wr * 32 + m * 16 + fr) * 40 + fq * 8;
        s16x8 afh = *(const s16x8*)&Ah[ao];
        s16x8 afl = *(const s16x8*)&Al[ao];
        acc[m][n] =
            __builtin_amdgcn_mfma_f32_16x16x32_bf16(afh, bfh, acc[m][n], 0, 0, 0);
        acc[m][n] =
            __builtin_amdgcn_mfma_f32_16x16x32_bf16(afh, bfl, acc[m][n], 0, 0, 0);
        acc[m][n] =
            __builtin_amdgcn_mfma_f32_16x16x32_bf16(afl, bfh, acc[m][n], 0, 0, 0);
      }
    }
  }

  float* Cf = head ? e_h : e_t;
  short* Ch = head ? eh_hi : et_hi;
  short* Cl = head ? eh_lo : et_lo;
  const int rbase = head ? row0 : row0 - 1024;
#pragma unroll
  for (int m = 0; m < 2; ++m) {
#pragma unroll
    for (int n = 0; n < 2; ++n) {
#pragma unroll
      for (int r = 0; r < 4; ++r) {
        int rg = rbase + wr * 32 + m * 16 + fq * 4 + r;
        int cg = col0 + wc * 32 + n * 16 + fr;
        float v = acc[m][n][r] + biasu[cg];
        size_t o = (size_t)rg * DDIM + cg;
        Cf[o] = v;
        short hh = f2bf(v);
        Ch[o] = hh;
        Cl[o] = f2bf(v - bf2f(hh));
      }
    }
  }
}

// -------- logits GEMM: 32x64 tiles, 512 blocks, batch->XCD affinity ------
__global__ __launch_bounds__(256) void gemm_logits(
    const short* __restrict__ eh_hi, const short* __restrict__ eh_lo,
    const short* __restrict__ et_hi, const short* __restrict__ et_lo,
    float* __restrict__ logits, float scale) {
  __shared__ short Ah[32 * 40], Al[32 * 40], Bh[64 * 40], Bl[64 * 40];
  const int bid = blockIdx.x;
  const int xcd = bid & 7, idx = bid >> 3;       // idx 0..63
  const int batch = xcd >> 1;                    // 2 XCDs per batch
  const int sub = ((xcd & 1) << 6) | idx;        // 0..127 tiles per batch
  const int xtile = sub & 15, ytile = sub >> 4;  // N=16 x-tiles, M=8 y-tiles
  const int row0 = ytile * 32, col0 = xtile * 64;
  const int t = threadIdx.x;

  // A staging: 32 rows x 4 chunks, hi(128)+lo(128) chunks over 256 threads
  const int ahalf = t >> 7, ac = t & 127;
  const int asr = ac >> 2, ask = (ac & 3) * 8;
  const short* aptr = (ahalf ? eh_lo : eh_hi) +
                      ((size_t)batch * NCLS + row0 + asr) * DDIM + ask;
  short* adst = (ahalf ? Al : Ah) + asr * 40 + ask;
  // B staging: 64 rows x 4 chunks, each thread loads hi+lo at same spot
  const int bsr = t >> 2, bsk = (t & 3) * 8;
  const short* bph = et_hi + ((size_t)batch * NTOK + col0 + bsr) * DDIM + bsk;
  const short* bpl = et_lo + ((size_t)batch * NTOK + col0 + bsr) * DDIM + bsk;
  short* bdh = Bh + bsr * 40 + bsk;
  short* bdl = Bl + bsr * 40 + bsk;

  const int lane = t & 63, wave = t >> 6;
  const int wr = wave >> 1, wc = wave & 1;  // wave: 16 rows x 32 cols
  const int fr = lane & 15, fq = lane >> 4;

  f32x4 acc[2] = {};
  for (int k0 = 0; k0 < DDIM; k0 += 32) {
    s16x8 av = *(const s16x8*)(aptr + k0);
    s16x8 bh = *(const s16x8*)(bph + k0);
    s16x8 bl = *(const s16x8*)(bpl + k0);
    __syncthreads();
    *(s16x8*)adst = av;
    *(s16x8*)bdh = bh;
    *(s16x8*)bdl = bl;
    __syncthreads();
    int ao = (wr * 16 + fr) * 40 + fq * 8;
    s16x8 afh = *(const s16x8*)&Ah[ao];
    s16x8 afl = *(const s16x8*)&Al[ao];
#pragma unroll
    for (int n = 0; n < 2; ++n) {
      int bo = (wc * 32 + n * 16 + fr) * 40 + fq * 8;
      s16x8 bfh = *(const s16x8*)&Bh[bo];
      s16x8 bfl = *(const s16x8*)&Bl[bo];
      acc[n] = __builtin_amdgcn_mfma_f32_16x16x32_bf16(afh, bfh, acc[n], 0, 0, 0);
      acc[n] = __builtin_amdgcn_mfma_f32_16x16x32_bf16(afh, bfl, acc[n], 0, 0, 0);
      acc[n] = __builtin_amdgcn_mfma_f32_16x16x32_bf16(afl, bfh, acc[n], 0, 0, 0);
    }
  }

  float* Cb = logits + (size_t)batch * NCLS * NTOK;
#pragma unroll
  for (int n = 0; n < 2; ++n)
#pragma unroll
    for (int r = 0; r < 4; ++r) {
      int rg = row0 + wr * 16 + fq * 4 + r;
      int cg = col0 + wc * 32 + n * 16 + fr;
      Cb[(size_t)rg * NTOK + cg] = scale * acc[n][r];
    }
}

// -------- lin GEMM (fused lin1/lin2), 64x64, plain bf16, leaky,
//          XCD-chunked (384 = 8 x 48) ----------
__global__ __launch_bounds__(256) void gemm_lin(
    const short* __restrict__ inbf, const short* __restrict__ L1T,
    const short* __restrict__ L2T, const float* __restrict__ b1,
    const float* __restrict__ b2, float* __restrict__ C) {
  __shared__ short Ah[64 * 40], Bh[64 * 40];
  const int bid = blockIdx.x;
  const int xcd = bid & 7, idx = bid >> 3;  // 0..47
  const int ytile = xcd * 4 + idx / 12, xtile = idx % 12;
  const int t = threadIdx.x;
  const int row0 = ytile * 64, col0 = xtile * 64;
  const bool second = row0 >= 1024;
  const int sr = t >> 2, sk = (t & 3) * 8;
  const short* aptr = inbf + (size_t)(row0 + sr) * DDIM + sk;
  const short* bptr = (second ? L2T : L1T) + (size_t)(col0 + sr) * DDIM + sk;
  const float* biasu = second ? b2 : b1;
  const int lane = t & 63, wave = t >> 6;
  const int wr = wave >> 1, wc = wave & 1;
  const int fr = lane & 15, fq = lane >> 4;

  f32x4 acc[2][2] = {};
  for (int k0 = 0; k0 < DDIM; k0 += 32) {
    s16x8 ah = *(const s16x8*)(aptr + k0);
    s16x8 bh = *(const s16x8*)(bptr + k0);
    __syncthreads();
    *(s16x8*)&Ah[sr * 40 + sk] = ah;
    *(s16x8*)&Bh[sr * 40 + sk] = bh;
    __syncthreads();
#pragma unroll
    for (int n = 0; n < 2; ++n) {
      int bo = (wc * 32 + n * 16 + fr) * 40 + fq * 8;
      s16x8 bfh = *(const s16x8*)&Bh[bo];
#pragma unroll
      for (int m = 0; m < 2; ++m) {
        int ao = (wr * 32 + m * 16 + fr) * 40 + fq * 8;
        s16x8 afh = *(const s16x8*)&Ah[ao];
        acc[m][n] =
            __builtin_amdgcn_mfma_f32_16x16x32_bf16(afh, bfh, acc[m][n], 0, 0, 0);
      }
    }
  }
#pragma unroll
  for (int m = 0; m < 2; ++m)
#pragma unroll
    for (int n = 0; n < 2; ++n)
#pragma unroll
      for (int r = 0; r < 4; ++r) {
        int rg = row0 + wr * 32 + m * 16 + fq * 4 + r;
        int cg = col0 + wc * 32 + n * 16 + fr;
        float v = acc[m][n][r] + biasu[cg];
        v = v > 0.f ? v : 0.01f * v;
        C[(size_t)rg * DDIM + cg] = v;
      }
}

// -------- top-k via 4-round byte radix select (set semantics) ------------
// Selects the exact top-128 set (ties -> smaller index), order arbitrary
// (downstream is permutation-invariant in k).
__global__ __launch_bounds__(256) void topk_select(
    const float* __restrict__ logits, float* __restrict__ tw,
    int* __restrict__ ti) {
  const int row = blockIdx.x;
  const int t = threadIdx.x;
  const int lane = t & 63, wave = t >> 6;
  __shared__ int hist[256];
  __shared__ int sh_bin, sh_rem;
  __shared__ int cnt;
  __shared__ int wsumT[4];

  float4 v4 = *(const float4*)(logits + (size_t)row * NTOK + 4 * t);
  float val[4] = {v4.x, v4.y, v4.z, v4.w};
  unsigned key[4];
#pragma unroll
  for (int i = 0; i < 4; ++i) {
    unsigned u = __float_as_uint(val[i]);
    key[i] = (u & 0x80000000u) ? ~u : (u | 0x80000000u);
  }

  unsigned pref = 0, mask = 0;
  int rem = KSEL;
#pragma unroll
  for (int shift = 24; shift >= 0; shift -= 8) {
    hist[t] = 0;
    __syncthreads();
#pragma unroll
    for (int i = 0; i < 4; ++i)
      if ((key[i] & mask) == pref)
        atomicAdd(&hist[(key[i] >> shift) & 255], 1);
    __syncthreads();
    if (wave == 0) {
      int h0 = hist[4 * lane], h1 = hist[4 * lane + 1];
      int h2 = hist[4 * lane + 2], h3 = hist[4 * lane + 3];
      int s = h0 + h1 + h2 + h3;
#pragma unroll
      for (int o = 1; o < 64; o <<= 1) {
        int v = __shfl_down(s, o, 64);
        if (lane + o < 64) s += v;
      }
      int abv = __shfl_down(s, 1, 64);
      if (lane == 63) abv = 0;
      int c3 = abv + h3, c2 = c3 + h2, c1 = c2 + h1, c0 = c1 + h0;
      int bin = -1, nab = 0;
      if (c3 >= rem && abv < rem) { bin = 4 * lane + 3; nab = abv; }
      else if (c2 >= rem && c3 < rem) { bin = 4 * lane + 2; nab = c3; }
      else if (c1 >= rem && c2 < rem) { bin = 4 * lane + 1; nab = c2; }
      else if (c0 >= rem && c1 < rem) { bin = 4 * lane + 0; nab = c1; }
      if (bin >= 0) { sh_bin = bin; sh_rem = rem - nab; }
    }
    __syncthreads();
    pref |= ((unsigned)sh_bin) << shift;
    mask |= 0xFFu << shift;
    rem = sh_rem;
  }

  const unsigned T = pref;
  const int above = KSEL - rem;  // count of keys strictly > T

  if (t == 0) cnt = 0;
  // exclusive scan (thread order == index order) of per-thread tie counts
  int tc = 0;
#pragma unroll
  for (int i = 0; i < 4; ++i) tc += (key[i] == T);
  int inc = tc;
#pragma unroll
  for (int o = 1; o < 64; o <<= 1) {
    int v = __shfl_up(inc, o, 64);
    if (lane >= o) inc += v;
  }
  if (lane == 63) wsumT[wave] = inc;
  __syncthreads();
  int wbase = 0;
#pragma unroll
  for (int w = 0; w < 4; ++w)
    if (w < wave) wbase += wsumT[w];
  int excl = wbase + inc - tc;

  float* twr = tw + (size_t)row * KSEL;
  int* tir = ti + (size_t)row * KSEL;
#pragma unroll
  for (int i = 0; i < 4; ++i) {
    if (key[i] > T) {
      int slot = atomicAdd(&cnt, 1);
      twr[slot] = val[i];
      tir[slot] = 4 * t + i;
    } else if (key[i] == T) {
      int r = excl++;
      if (r < rem) {
        twr[above + r] = val[i];
        tir[above + r] = 4 * t + i;
      }
    }
  }
}

// -------- agg1: gated ka weights (2 blocks/row, XCD-batch affinity) ------
__global__ __launch_bounds__(256) void agg1(const float* __restrict__ e_h,
                                            const float* __restrict__ e_t,
                                            const float* __restrict__ tw,
                                            const int* __restrict__ ti,
                                            float* __restrict__ kaw_raw) {
  const int bid = blockIdx.x;
  const int xcd = bid & 7, slot = bid >> 3;
  const int batch = xcd >> 1;
  const int u = ((xcd & 1) << 8) | slot;
  const int row = batch * 256 + (u >> 1);
  const int half = u & 1;
  const int t = threadIdx.x, lane = t & 63, wave = t >> 6;
  __shared__ float p[KSEL];
  __shared__ int idxs[KSEL];
  __shared__ float red[2];

  if (t < KSEL) {
    p[t] = tw[(size_t)row * KSEL + t];
    idxs[t] = ti[(size_t)row * KSEL + t];
  }
  __syncthreads();
  if (wave == 0) {
    float m = wmaxr(fmaxf(p[lane], p[lane + 64]));
    if (!lane) red[0] = m;
  }
  __syncthreads();
  if (t < KSEL) p[t] = __expf(p[t] - red[0]);
  __syncthreads();
  if (wave == 0) {
    float s = wsum(p[lane] + p[lane + 64]);
    if (!lane) red[1] = s;
  }
  __syncthreads();
  if (t < KSEL) p[t] *= (1.f / red[1]);
  __syncthreads();

  float ehr[12];
  {
    const float* ehrow = e_h + (size_t)row * DDIM;
#pragma unroll
    for (int c = 0; c < 3; ++c) {
      float4 v = *(const float4*)(ehrow + 4 * lane + 256 * c);
      ehr[4 * c + 0] = v.x;
      ehr[4 * c + 1] = v.y;
      ehr[4 * c + 2] = v.z;
      ehr[4 * c + 3] = v.w;
    }
  }
  const float* etb = e_t + (size_t)batch * NTOK * DDIM;

  for (int i = 0; i < 16; ++i) {
    int j = half * 64 + wave * 16 + i;
    float pj = p[j];
    float a = 4.f - 2.f * pj, b2 = 2.f * pj;
    const float* nb = etb + (size_t)idxs[j] * DDIM;
    float partial = 0.f;
#pragma unroll
    for (int c = 0; c < 3; ++c) {
      float4 nv = *(const float4*)(nb + 4 * lane + 256 * c);
      float nq[4] = {nv.x, nv.y, nv.z, nv.w};
#pragma unroll
      for (int q = 0; q < 4; ++q) {
        float y2 = fmaf(a, ehr[4 * c + q], b2 * nq[q]);
        float ex = __expf(y2);
        float g = fmaf(-2.f, __builtin_amdgcn_rcpf(1.f + ex), 1.f);
        partial = fmaf(nq[q], g, partial);
      }
    }
    partial = wsum(partial);
    if (!lane) kaw_raw[(size_t)row * KSEL + j] = partial;
  }
}

// -------- agg2: ka softmax + weighted sum -> bf16 lin inputs -------------
__global__ __launch_bounds__(192) void agg2(
    const float* __restrict__ e_h, const float* __restrict__ e_t,
    const float* __restrict__ cls, const float* __restrict__ kaw_raw,
    const int* __restrict__ ti, short* __restrict__ inbf) {
  const int bid = blockIdx.x;
  const int xcd = bid & 7, slot = bid >> 3;
  const int batch = xcd >> 1;
  const int row = batch * 256 + (xcd & 1) * 128 + slot;
  const int t = threadIdx.x, lane = t & 63, wave = t >> 6;
  __shared__ float kp[KSEL];
  __shared__ int idxs[KSEL];
  __shared__ float red[2];

  if (t < KSEL) {
    kp[t] = kaw_raw[(size_t)row * KSEL + t];
    idxs[t] = ti[(size_t)row * KSEL + t];
  }
  __syncthreads();
  if (wave == 0) {
    float m = wmaxr(fmaxf(kp[lane], kp[lane + 64]));
    if (!lane) red[0] = m;
  }
  __syncthreads();
  if (t < KSEL) kp[t] = __expf(kp[t] - red[0]);
  __syncthreads();
  if (wave == 0) {
    float s = wsum(kp[lane] + kp[lane + 64]);
    if (!lane) red[1] = s;
  }
  __syncthreads();
  if (t < KSEL) kp[t] *= (1.f / red[1]);
  __syncthreads();

  const size_t o = (size_t)row * DDIM + 4 * t;
  float4 eh4 = *(const float4*)(e_h + o);
  float4 cl4 = *(const float4*)(cls + o);
  const float* etb = e_t + (size_t)batch * NTOK * DDIM;

  float ax = 0.f, ay = 0.f, az = 0.f, aw = 0.f;
#pragma unroll 8
  for (int j = 0; j < KSEL; ++j) {
    float pr = kp[j];
    float4 nb = *(const float4*)(etb + (size_t)idxs[j] * DDIM + 4 * t);
    ax = fmaf(pr, nb.x, ax);
    ay = fmaf(pr, nb.y, ay);
    az = fmaf(pr, nb.z, az);
    aw = fmaf(pr, nb.w, aw);
  }

  short4 sv, bv;
  sv.x = f2bf((eh4.x + ax) * 0.1f + cl4.x);
  sv.y = f2bf((eh4.y + ay) * 0.1f + cl4.y);
  sv.z = f2bf((eh4.z + az) * 0.1f + cl4.z);
  sv.w = f2bf((eh4.w + aw) * 0.1f + cl4.w);
  bv.x = f2bf((eh4.x * ax) * 0.1f + cl4.x);
  bv.y = f2bf((eh4.y * ay) * 0.1f + cl4.y);
  bv.z = f2bf((eh4.z * az) * 0.1f + cl4.z);
  bv.w = f2bf((eh4.w * aw) * 0.1f + cl4.w);
  *(short4*)&inbf[o] = sv;
  *(short4*)&inbf[(size_t)(NBATCH * NCLS) * DDIM + o] = bv;
}

// -------- layernorm over D=768 on (embA[row] + embB[row]) --------
__global__ __launch_bounds__(256) void ln_kernel(const float* __restrict__ embA,
                                                 const float* __restrict__ embB,
                                                 const float* __restrict__ lw,
                                                 const float* __restrict__ lb,
                                                 float* __restrict__ out) {
  const int row = blockIdx.x;
  const int t = threadIdx.x;
  const int lane = t & 63, wave = t >> 6;
  __shared__ float red[4];
  __shared__ float bs[2];
  float e[3];
#pragma unroll
  for (int c = 0; c < 3; ++c) {
    size_t o = (size_t)row * DDIM + t + 256 * c;
    e[c] = embA[o] + embB[o];
  }
  float s = e[0] + e[1] + e[2];
  s = wsum(s);
  if (lane == 0) red[wave] = s;
  __syncthreads();
  if (t == 0) bs[0] = (red[0] + red[1] + red[2] + red[3]) * (1.f / DDIM);
  __syncthreads();
  float mu = bs[0];
  float q = 0.f;
#pragma unroll
  for (int c = 0; c < 3; ++c) {
    float d = e[c] - mu;
    q = fmaf(d, d, q);
  }
  q = wsum(q);
  if (lane == 0) red[wave] = q;
  __syncthreads();
  if (t == 0) bs[1] = (red[0] + red[1] + red[2] + red[3]) * (1.f / DDIM);
  __syncthreads();
  float rstd = rsqrtf(bs[1] + 1e-5f);
#pragma unroll
  for (int c = 0; c < 3; ++c) {
    int d = t + 256 * c;
    out[(size_t)row * DDIM + d] = (e[c] - mu) * rstd * lw[d] + lb[d];
  }
}

// ---------------- launch ----------------
extern "C" void kernel_launch(void* const* d_in, const int* in_sizes, int n_in,
                              void* d_out, int out_size, void* d_ws,
                              size_t ws_size, hipStream_t stream) {
  const float* cls = (const float*)d_in[0];
  const float* feats = (const float*)d_in[1];
  const float* Whw = (const float*)d_in[2];
  const float* Whb = (const float*)d_in[3];
  const float* Wtw = (const float*)d_in[4];
  const float* Wtb = (const float*)d_in[5];
  const float* l1w = (const float*)d_in[6];
  const float* l1b = (const float*)d_in[7];
  const float* l2w = (const float*)d_in[8];
  const float* l2b = (const float*)d_in[9];
  const float* lnw = (const float*)d_in[10];
  const float* lnb = (const float*)d_in[11];
  float* out = (float*)d_out;

  float* ws = (float*)d_ws;
  // layout (float units)
  float* e_h = ws;                          // 786432
  float* e_t = ws + 786432;                 // 3145728
  short* eh_hi = (short*)(ws + 3932160);    // 786432 shorts
  short* eh_lo = eh_hi + 786432;            // (ends 4718592f)
  short* et_hi = (short*)(ws + 4718592);    // 3145728 shorts
  short* et_lo = et_hi + 3145728;           // (ends 7864320f)
  short* WhT_h = (short*)(ws + 7864320);    // 589824 shorts each
  short* WhT_l = WhT_h + 589824;
  short* WtT_h = WhT_h + 2 * 589824;
  short* WtT_l = WhT_h + 3 * 589824;        // (ends 9043968f)
  short* L1T = (short*)(ws + 9043968);      // 589824 shorts
  short* L2T = L1T + 589824;                // (ends 9633792f)
  float* logits = ws + 7864320;             // overlays WhT/WtT (dead by then)
  float* tw = ws + 9633792;                 // 131072
  int* ti = (int*)(ws + 9764864);           // 131072
  float* kaw = ws + 9895936;                // 131072
  short* inbf = (short*)(ws + 10027008);    // 2048*768 shorts (786432 f)
  float* linC = e_t;                        // overlays e_t (dead after agg2)
  (void)ws_size;
  (void)in_sizes;
  (void)n_in;
  (void)out_size;

  const float scale = 0.036084391824351615f;  // 1/sqrt(768)
  dim3 blk(256);

  // weights -> transposed bf16 (hi/lo for Wh/Wt, plain for L1/L2)
  prep_weights<<<dim3(24, 24, 4), blk, 0, stream>>>(
      Whw, Wtw, l1w, l2w, WhT_h, WtT_h, L1T, L2T, WhT_l, WtT_l);
  // fused e_h | e_t (960 blocks, XCD-chunked)
  gemm_front<<<dim3(960), blk, 0, stream>>>(
      cls, feats, WhT_h, WhT_l, Whb, WtT_h, WtT_l, Wtb, e_h, eh_hi, eh_lo, e_t,
      et_hi, et_lo);
  // logits[b] = scale * e_h[b] @ e_t[b]^T (512 blocks, batch->XCD affinity)
  gemm_logits<<<dim3(512), blk, 0, stream>>>(eh_hi, eh_lo, et_hi, et_lo,
                                             logits, scale);
  // top-128 per row (radix select)
  topk_select<<<dim3(NBATCH * NCLS), blk, 0, stream>>>(logits, tw, ti);
  // agg1: gated ka weights (2048 blocks)
  agg1<<<dim3(2048), blk, 0, stream>>>(e_h, e_t, tw, ti, kaw);
  // agg2: softmax + weighted sum -> bf16 lin inputs
  agg2<<<dim3(1024), dim3(192), 0, stream>>>(e_h, e_t, cls, kaw, ti, inbf);
  // fused lin1/lin2 (384 blocks, XCD-chunked): rows<1024 -> l1, else l2
  gemm_lin<<<dim3(384), blk, 0, stream>>>(inbf, L1T, L2T, l1b, l2b, linC);
  // layernorm(sum_emb + bi_emb) -> out
  ln_kernel<<<dim3(NBATCH * NCLS), blk, 0, stream>>>(
      linC, linC + (size_t)(NBATCH * NCLS) * DDIM, lnw, lnb, out);
}